// Round 5
// baseline (1289.603 us; speedup 1.0000x reference)
//
#include <hip/hip_runtime.h>
#include <hip/hip_bf16.h>
#include <hip/hip_fp16.h>
#include <math.h>

#define N_USERS 100000
#define N_ITEMS 50000
#define N_NODES 150000
#define DD 64
#define E_G 3200000
#define EU 1600000
#define EI 800000
#define E_HAN 4800000
#define NH 300000
#define NBG 293        // ceil(150000/512)
#define NBH 586        // ceil(300000/512)
#define ROWS 32
#define NBU 3125       // ceil(100000/32)
#define NBI 1563       // ceil(50000/32)

typedef float v2f __attribute__((ext_vector_type(2)));

__device__ __forceinline__ float invdeg(float d){
  return d > 0.f ? rsqrtf(fmaxf(d, 1e-12f)) : 0.f;
}
__device__ __forceinline__ float tanh_fast(float x){
  float cx = fminf(15.f, fmaxf(-15.f, x));
  float t = __expf(2.f*cx);
  return (t - 1.f)/(t + 1.f);
}
__device__ __forceinline__ unsigned short f2b(float x){
  unsigned int b = __float_as_uint(x);
  b += 0x7FFFu + ((b >> 16) & 1u);
  return (unsigned short)(b >> 16);
}
__device__ __forceinline__ float b2f(unsigned short u){
  return __uint_as_float(((unsigned int)u) << 16);
}
// unpack 2 bf16 (lo,hi) from one uint into a float2 vector (pk_fma friendly)
__device__ __forceinline__ v2f b2f2(unsigned int u){
  v2f r;
  r.x = __uint_as_float(u << 16);
  r.y = __uint_as_float(u & 0xFFFF0000u);
  return r;
}
__device__ __forceinline__ unsigned short f2h(float x){
  return __half_as_ushort(__float2half(x));
}
__device__ __forceinline__ float h2f(unsigned short u){
  return __half2float(__ushort_as_half(u));
}
__device__ __forceinline__ v2f h2v2(unsigned int u){
  __half2 h = *reinterpret_cast<__half2*>(&u);
  float2 t = __half22float2(h);
  v2f r; r.x = t.x; r.y = t.y;
  return r;
}

__global__ void k_init(const float* __restrict__ fu, const float* __restrict__ fi,
                       float* __restrict__ cur, unsigned short* __restrict__ curh,
                       float* __restrict__ total){
  int i = blockIdx.x*256 + threadIdx.x;
  if (i >= N_NODES*DD) return;
  float v = (i < N_USERS*DD) ? fu[i] : fi[i - N_USERS*DD];
  cur[i] = v; total[i] = v; curh[i] = f2h(v);
}

// ---------------- generic scan helpers ----------------
__global__ __launch_bounds__(256) void k_colscan(int* __restrict__ wh, int nb,
                                                 int* __restrict__ colsum){
  __shared__ int s[256];
  int b = blockIdx.x, tid = threadIdx.x;
  int v = wh[tid*nb + b];
  s[tid] = v; __syncthreads();
  for (int o = 1; o < 256; o <<= 1){
    int t = (tid >= o) ? s[tid - o] : 0;
    __syncthreads();
    s[tid] += t;
    __syncthreads();
  }
  wh[tid*nb + b] = s[tid] - v;
  if (tid == 255) colsum[b] = s[255];
}

__global__ __launch_bounds__(256) void k_bscan(const int* __restrict__ colsum, int nb,
                                               int total, int* __restrict__ bB){
  __shared__ int s[256];
  __shared__ int carry;
  int tid = threadIdx.x;
  if (tid == 0) carry = 0;
  __syncthreads();
  for (int base = 0; base < nb; base += 256){
    int i = base + tid;
    int v = (i < nb) ? colsum[i] : 0;
    s[tid] = v; __syncthreads();
    for (int o = 1; o < 256; o <<= 1){
      int t = (tid >= o) ? s[tid - o] : 0;
      __syncthreads();
      s[tid] += t;
      __syncthreads();
    }
    int c = carry;
    if (i < nb) bB[i] = c + s[tid] - v;
    __syncthreads();
    if (tid == 255) carry = c + s[255];
    __syncthreads();
  }
  if (tid == 0) bB[nb] = total;
}

// ---------------- G build ----------------
__global__ __launch_bounds__(256) void k_h1_g(const int* __restrict__ gi,
                                              int* __restrict__ wh){
  __shared__ int h[NBG];
  int tid = threadIdx.x;
  for (int b = tid; b < NBG; b += 256) h[b] = 0;
  __syncthreads();
  int e0 = blockIdx.x*(E_G/256);
  for (int i = tid; i < E_G/256; i += 256)
    atomicAdd(&h[gi[e0 + i] >> 9], 1);
  __syncthreads();
  for (int b = tid; b < NBG; b += 256) wh[blockIdx.x*NBG + b] = h[b];
}

__global__ __launch_bounds__(256) void k_h2_g(const int* __restrict__ gi,
        const float* __restrict__ gv, const int* __restrict__ wh,
        const int* __restrict__ bB, uint2* __restrict__ kv){
  __shared__ int lcur[NBG];
  int tid = threadIdx.x, wg = blockIdx.x;
  for (int b = tid; b < NBG; b += 256) lcur[b] = bB[b] + wh[wg*NBG + b];
  __syncthreads();
  int e0 = wg*(E_G/256);
  for (int i = tid; i < E_G/256; i += 256){
    int e = e0 + i;
    int d = gi[e];
    int p = atomicAdd(&lcur[d >> 9], 1);
    uint2 r;
    r.x = ((unsigned)(d & 511) << 18) | (unsigned)gi[E_G + e];
    r.y = __float_as_uint(gv[e]);
    kv[p] = r;
  }
}

__global__ __launch_bounds__(256) void k_p2_g(const int* __restrict__ bB,
        const uint2* __restrict__ kv, int* __restrict__ off,
        unsigned int* __restrict__ packed){
  __shared__ int cnt[512], sc[512], lcur[512];
  int b = blockIdx.x, tid = threadIdx.x;
  int d0 = b << 9;
  int dcnt = min(512, N_NODES - d0);
  int pb = bB[b], pe = bB[b+1];
  for (int i = tid; i < 512; i += 256) cnt[i] = 0;
  __syncthreads();
  for (int p = pb + tid; p < pe; p += 256)
    atomicAdd(&cnt[kv[p].x >> 18], 1);
  __syncthreads();
  sc[tid] = cnt[tid]; sc[tid + 256] = cnt[tid + 256];
  __syncthreads();
  for (int o = 1; o < 512; o <<= 1){
    int a0 = (tid >= o) ? sc[tid - o] : 0;
    int a1 = sc[tid + 256 - o];
    __syncthreads();
    sc[tid] += a0; sc[tid + 256] += a1;
    __syncthreads();
  }
  for (int i = tid; i < 512; i += 256) lcur[i] = pb + sc[i] - cnt[i];
  for (int i = tid; i < dcnt; i += 256) off[d0 + i] = pb + sc[i] - cnt[i];
  if (tid == 0) off[d0 + dcnt] = pe;
  __syncthreads();
  for (int p = pb + tid; p < pe; p += 256){
    uint2 r = kv[p];
    int dl = (int)(r.x >> 18);
    unsigned int s = r.x & 0x3FFFFu;
    float v = __uint_as_float(r.y);
    int q14 = (int)(v*16383.f + 0.5f);
    if (q14 > 16383) q14 = 16383;
    int q = atomicAdd(&lcur[dl], 1);
    packed[q] = (s << 14) | (unsigned int)q14;
  }
}

// ---------------- DCCF spmm gather (packed CSR, f16 table, 2 gathers in flight) ----
__global__ __launch_bounds__(256) void k_spmm_gp(const int* __restrict__ off,
        const unsigned int* __restrict__ packed,
        const unsigned short* __restrict__ curh, unsigned short* __restrict__ gnnh){
  int wv = threadIdx.x >> 6, lane = threadIdx.x & 63;
  int node = blockIdx.x*4 + wv;
  if (node >= N_NODES) return;
  int b = off[node], e = off[node+1];
  int c8 = (lane & 7)*8, sl = lane >> 3;
  const float inv14 = 1.f/16383.f;
  v2f a0 = {0.f,0.f}, a1 = {0.f,0.f}, a2 = {0.f,0.f}, a3 = {0.f,0.f};
  for (int k = b; k < e; k += 16){
    int i0 = k + sl, i1 = i0 + 8;
    unsigned int pk0 = (i0 < e) ? packed[i0] : 0u;   // pk==0 -> weight 0
    unsigned int pk1 = (i1 < e) ? packed[i1] : 0u;
    int s0 = (int)(pk0 >> 14), s1 = (int)(pk1 >> 14);
    float w0 = (float)(pk0 & 16383u) * inv14;
    float w1 = (float)(pk1 & 16383u) * inv14;
    const uint4 u0 = *(const uint4*)&curh[s0*DD + c8];
    const uint4 u1 = *(const uint4*)&curh[s1*DD + c8];
    a0 += w0 * h2v2(u0.x); a1 += w0 * h2v2(u0.y);
    a2 += w0 * h2v2(u0.z); a3 += w0 * h2v2(u0.w);
    a0 += w1 * h2v2(u1.x); a1 += w1 * h2v2(u1.y);
    a2 += w1 * h2v2(u1.z); a3 += w1 * h2v2(u1.w);
  }
  float a[8] = {a0.x,a0.y,a1.x,a1.y,a2.x,a2.y,a3.x,a3.y};
  #pragma unroll
  for (int j = 0; j < 8; ++j){
    a[j] += __shfl_xor(a[j], 8, 64);
    a[j] += __shfl_xor(a[j], 16, 64);
    a[j] += __shfl_xor(a[j], 32, 64);
  }
  if (lane < 8){
    uint4 o;
    o.x = (unsigned)f2h(a[0]) | ((unsigned)f2h(a[1]) << 16);
    o.y = (unsigned)f2h(a[2]) | ((unsigned)f2h(a[3]) << 16);
    o.z = (unsigned)f2h(a[4]) | ((unsigned)f2h(a[5]) << 16);
    o.w = (unsigned)f2h(a[6]) | ((unsigned)f2h(a[7]) << 16);
    *(uint4*)&gnnh[node*DD + c8] = o;
  }
}

// ---------------- intent (tiled GEMM, user+item merged) ----------------
__global__ __launch_bounds__(256) void k_intent2(const float* __restrict__ u_int,
        const float* __restrict__ i_int,
        const unsigned short* __restrict__ gnnh, float* __restrict__ cur,
        unsigned short* __restrict__ curh, float* __restrict__ total){
  __shared__ float sB[64*132];
  __shared__ float sU[ROWS*132];
  int tid = threadIdx.x, tx = tid & 15, ty = tid >> 4;
  int bid = blockIdx.x;
  const float* intent; int base, nrows, lb;
  if (bid < NBU){ intent = u_int; base = 0; nrows = N_USERS; lb = bid; }
  else          { intent = i_int; base = N_USERS; nrows = N_ITEMS; lb = bid - NBU; }

  for (int i = tid; i < 2048; i += 256){
    int r = i >> 5, c = (i & 31) << 2;
    *(float4*)&sB[r*132 + c] = *(const float4*)&intent[r*128 + c];
  }
  {
    int r = tid & 31, q0 = tid >> 5;
    int rr = lb*ROWS + r;
    int rowg = base + (rr < nrows ? rr : nrows - 1);
    for (int q = q0; q < 16; q += 8){
      float4 v = *(const float4*)&cur[rowg*DD + 4*q];
      sU[(4*q+0)*36 + r] = v.x;
      sU[(4*q+1)*36 + r] = v.y;
      sU[(4*q+2)*36 + r] = v.z;
      sU[(4*q+3)*36 + r] = v.w;
    }
  }
  __syncthreads();

  float w[2][8];
  #pragma unroll
  for (int i = 0; i < 2; ++i)
    #pragma unroll
    for (int k = 0; k < 8; ++k) w[i][k] = 0.f;
  for (int d = 0; d < 64; ++d){
    float2 a = *(const float2*)&sU[d*36 + 2*ty];
    float4 b0 = *(const float4*)&sB[d*132 + 8*tx];
    float4 b1 = *(const float4*)&sB[d*132 + 8*tx + 4];
    float bb[8] = {b0.x,b0.y,b0.z,b0.w,b1.x,b1.y,b1.z,b1.w};
    #pragma unroll
    for (int k = 0; k < 8; ++k){ w[0][k] += a.x*bb[k]; w[1][k] += a.y*bb[k]; }
  }

  float p[2][8];
  #pragma unroll
  for (int i = 0; i < 2; ++i){
    float mx = w[i][0];
    #pragma unroll
    for (int k = 1; k < 8; ++k) mx = fmaxf(mx, w[i][k]);
    mx = fmaxf(mx, __shfl_xor(mx, 1, 64));
    mx = fmaxf(mx, __shfl_xor(mx, 2, 64));
    mx = fmaxf(mx, __shfl_xor(mx, 4, 64));
    mx = fmaxf(mx, __shfl_xor(mx, 8, 64));
    float s = 0.f;
    #pragma unroll
    for (int k = 0; k < 8; ++k){ p[i][k] = __expf(w[i][k] - mx); s += p[i][k]; }
    s += __shfl_xor(s, 1, 64);
    s += __shfl_xor(s, 2, 64);
    s += __shfl_xor(s, 4, 64);
    s += __shfl_xor(s, 8, 64);
    float inv = 1.f / s;
    #pragma unroll
    for (int k = 0; k < 8; ++k) p[i][k] *= inv;
  }
  __syncthreads();
  #pragma unroll
  for (int i = 0; i < 2; ++i){
    *(float4*)&sU[(2*ty+i)*132 + 8*tx]     = make_float4(p[i][0],p[i][1],p[i][2],p[i][3]);
    *(float4*)&sU[(2*ty+i)*132 + 8*tx + 4] = make_float4(p[i][4],p[i][5],p[i][6],p[i][7]);
  }
  __syncthreads();

  float o[2][4];
  #pragma unroll
  for (int i = 0; i < 2; ++i)
    #pragma unroll
    for (int m = 0; m < 4; ++m) o[i][m] = 0.f;
  for (int q = 0; q < 32; ++q){
    float4 p0 = *(const float4*)&sU[(2*ty+0)*132 + 4*q];
    float4 p1 = *(const float4*)&sU[(2*ty+1)*132 + 4*q];
    #pragma unroll
    for (int m = 0; m < 4; ++m){
      float4 bl = *(const float4*)&sB[(4*tx+m)*132 + 4*q];
      o[0][m] += p0.x*bl.x + p0.y*bl.y + p0.z*bl.z + p0.w*bl.w;
      o[1][m] += p1.x*bl.x + p1.y*bl.y + p1.z*bl.z + p1.w*bl.w;
    }
  }

  #pragma unroll
  for (int i = 0; i < 2; ++i){
    int rr = lb*ROWS + 2*ty + i;
    if (rr < nrows){
      int rowg = base + rr;
      ushort4 gh = *(const ushort4*)&gnnh[rowg*DD + 4*tx];
      float4 c = *(const float4*)&cur[rowg*DD + 4*tx];
      float4 t = *(const float4*)&total[rowg*DD + 4*tx];
      float4 cn = make_float4(h2f(gh.x) + o[i][0] + c.x, h2f(gh.y) + o[i][1] + c.y,
                              h2f(gh.z) + o[i][2] + c.z, h2f(gh.w) + o[i][3] + c.w);
      *(float4*)&cur[rowg*DD + 4*tx] = cn;
      ushort4 ch;
      ch.x = f2h(cn.x); ch.y = f2h(cn.y); ch.z = f2h(cn.z); ch.w = f2h(cn.w);
      *(ushort4*)&curh[rowg*DD + 4*tx] = ch;
      *(float4*)&total[rowg*DD + 4*tx] =
          make_float4(t.x + cn.x, t.y + cn.y, t.z + cn.z, t.w + cn.w);
    }
  }
}

// ---------------- HAN build ----------------
__device__ __forceinline__ void han_decode(int t, const int* mp_u, const int* mp_i,
                                           int* gs, int* gd){
  if (t < 2*EU){
    int s = (t < EU) ? 0 : 1;
    int e = t - s*EU;
    const int* sp = mp_u + (long)s*2*EU;
    int nb = s*N_USERS;
    *gs = nb + sp[e]; *gd = nb + sp[EU + e];
  } else {
    int t2 = t - 2*EU;
    int s = (t2 < EI) ? 0 : 1;
    int e = t2 - s*EI;
    const int* sp = mp_i + (long)s*2*EI;
    int nb = 2*N_USERS + s*N_ITEMS;
    *gs = nb + sp[e]; *gd = nb + sp[EI + e];
  }
}

// dst-bucket histogram (per-wg, LDS) — histogram only
__global__ __launch_bounds__(256) void k_h1_h(const int* __restrict__ mp_u,
        const int* __restrict__ mp_i, int* __restrict__ whD){
  __shared__ int hd[NBH];
  int tid = threadIdx.x;
  for (int b = tid; b < NBH; b += 256) hd[b] = 0;
  __syncthreads();
  int t0 = blockIdx.x*(E_HAN/256);
  for (int i = tid; i < E_HAN/256; i += 256){
    int gs, gd;
    han_decode(t0 + i, mp_u, mp_i, &gs, &gd);
    atomicAdd(&hd[gd >> 9], 1);
  }
  __syncthreads();
  for (int b = tid; b < NBH; b += 256)
    whD[blockIdx.x*NBH + b] = hd[b];
}

// src out-degree count: big grid, latency-hidden device atomics (src halves only)
__global__ __launch_bounds__(256) void k_dego(const int* __restrict__ mp_u,
        const int* __restrict__ mp_i, int* __restrict__ dego){
  int stride = gridDim.x*256;
  for (int t = blockIdx.x*256 + threadIdx.x; t < E_HAN; t += stride){
    int gs;
    if (t < 2*EU){
      int s = (t < EU) ? 0 : 1;
      int e = t - s*EU;
      gs = s*N_USERS + mp_u[(long)s*2*EU + e];
    } else {
      int t2 = t - 2*EU;
      int s = (t2 < EI) ? 0 : 1;
      int e = t2 - s*EI;
      gs = 2*N_USERS + s*N_ITEMS + mp_i[(long)s*2*EI + e];
    }
    atomicAdd(&dego[gs], 1);
  }
}

__global__ __launch_bounds__(256) void k_h2_h(const int* __restrict__ mp_u,
        const int* __restrict__ mp_i, const int* __restrict__ whD,
        const int* __restrict__ bBD, unsigned int* __restrict__ keyD){
  __shared__ int lcD[NBH];
  int tid = threadIdx.x, wg = blockIdx.x;
  for (int b = tid; b < NBH; b += 256)
    lcD[b] = bBD[b] + whD[wg*NBH + b];
  __syncthreads();
  int t0 = wg*(E_HAN/256);
  for (int i = tid; i < E_HAN/256; i += 256){
    int gs, gd;
    han_decode(t0 + i, mp_u, mp_i, &gs, &gd);
    int pD = atomicAdd(&lcD[gd >> 9], 1);
    keyD[pD] = ((unsigned)(gd & 511) << 19) | (unsigned)gs;
  }
}

// partition keyD by dst; pack ssrc = (feat_row(src) << 14) | q14(invdeg(degout[src]))
__global__ __launch_bounds__(256) void k_p2_h(const int* __restrict__ bB,
        const unsigned int* __restrict__ key, const int* __restrict__ dego,
        int* __restrict__ off, unsigned int* __restrict__ ssrc){
  __shared__ int cnt[512], sc[512], lcur[512];
  int b = blockIdx.x, tid = threadIdx.x;
  int d0 = b << 9;
  int dcnt = min(512, NH - d0);
  int pb = bB[b], pe = bB[b+1];
  for (int i = tid; i < 512; i += 256) cnt[i] = 0;
  __syncthreads();
  for (int p = pb + tid; p < pe; p += 256)
    atomicAdd(&cnt[key[p] >> 19], 1);
  __syncthreads();
  sc[tid] = cnt[tid]; sc[tid + 256] = cnt[tid + 256];
  __syncthreads();
  for (int o = 1; o < 512; o <<= 1){
    int a0 = (tid >= o) ? sc[tid - o] : 0;
    int a1 = sc[tid + 256 - o];
    __syncthreads();
    sc[tid] += a0; sc[tid + 256] += a1;
    __syncthreads();
  }
  for (int i = tid; i < 512; i += 256) lcur[i] = pb + sc[i] - cnt[i];
  for (int i = tid; i < dcnt; i += 256) off[d0 + i] = pb + sc[i] - cnt[i];
  if (tid == 0) off[d0 + dcnt] = pe;
  __syncthreads();
  for (int p = pb + tid; p < pe; p += 256){
    unsigned int k = key[p];
    int dl = (int)(k >> 19);
    int gs = (int)(k & 0x7FFFFu);
    // map HAN node id -> shared feature row [0,150000)
    int fsrc = gs - (gs >= N_USERS ? N_USERS : 0) - (gs >= 250000 ? 50000 : 0);
    float w = invdeg((float)dego[gs]);
    int q14 = (int)(w*16383.f + 0.5f);
    if (q14 > 16383) q14 = 16383;
    int q = atomicAdd(&lcur[dl], 1);
    ssrc[q] = ((unsigned)fsrc << 14) | (unsigned)q14;
  }
}

// fb[row] = bf16(feat[row]) for the shared 150K-row feature table
__global__ void k_fb(const float* __restrict__ fu, const float* __restrict__ fi,
                     unsigned short* __restrict__ fb){
  int i = blockIdx.x*256 + threadIdx.x;
  if (i >= N_NODES*DD) return;
  float f = (i < N_USERS*DD) ? fu[i] : fi[i - N_USERS*DD];
  fb[i] = f2b(f);
}

// z[g] (bf16) = invdeg(deg_in[g]) * sum q14(invdeg_out[src]) * fb[src]
// 8 lanes/edge x 16B loads, 16 edges per iteration, 2 gathers in flight/lane
__global__ __launch_bounds__(256) void k_han_gb(const int* __restrict__ off,
        const unsigned int* __restrict__ ssrc, const unsigned short* __restrict__ fb,
        unsigned short* __restrict__ zb){
  int wv = threadIdx.x >> 6, lane = threadIdx.x & 63;
  int g = blockIdx.x*4 + wv;
  if (g >= NH) return;
  int b = off[g], e = off[g+1];
  int c8 = (lane & 7)*8, sl = lane >> 3;
  const float inv14 = 1.f/16383.f;
  v2f a0 = {0.f,0.f}, a1 = {0.f,0.f}, a2 = {0.f,0.f}, a3 = {0.f,0.f};
  for (int k = b; k < e; k += 16){
    int i0 = k + sl, i1 = i0 + 8;
    unsigned int pk0 = (i0 < e) ? ssrc[i0] : 0u;   // pk==0 -> weight 0
    unsigned int pk1 = (i1 < e) ? ssrc[i1] : 0u;
    int s0 = (int)(pk0 >> 14), s1 = (int)(pk1 >> 14);
    float w0 = (float)(pk0 & 16383u) * inv14;
    float w1 = (float)(pk1 & 16383u) * inv14;
    const uint4 u0 = *(const uint4*)&fb[s0*DD + c8];
    const uint4 u1 = *(const uint4*)&fb[s1*DD + c8];
    a0 += w0 * b2f2(u0.x); a1 += w0 * b2f2(u0.y);
    a2 += w0 * b2f2(u0.z); a3 += w0 * b2f2(u0.w);
    a0 += w1 * b2f2(u1.x); a1 += w1 * b2f2(u1.y);
    a2 += w1 * b2f2(u1.z); a3 += w1 * b2f2(u1.w);
  }
  float a[8] = {a0.x,a0.y,a1.x,a1.y,a2.x,a2.y,a3.x,a3.y};
  #pragma unroll
  for (int j = 0; j < 8; ++j){
    a[j] += __shfl_xor(a[j], 8, 64);
    a[j] += __shfl_xor(a[j], 16, 64);
    a[j] += __shfl_xor(a[j], 32, 64);
  }
  if (lane < 8){
    float win = invdeg((float)(e - b));
    uint4 o;
    o.x = (unsigned)f2b(win*a[0]) | ((unsigned)f2b(win*a[1]) << 16);
    o.y = (unsigned)f2b(win*a[2]) | ((unsigned)f2b(win*a[3]) << 16);
    o.z = (unsigned)f2b(win*a[4]) | ((unsigned)f2b(win*a[5]) << 16);
    o.w = (unsigned)f2b(win*a[6]) | ((unsigned)f2b(win*a[7]) << 16);
    *(uint4*)&zb[g*DD + c8] = o;
  }
}

// semantic attention reduction (bf16 z input), user+item merged
__global__ __launch_bounds__(256) void k_sem2(const float* __restrict__ uW1,
        const float* __restrict__ ub1, const float* __restrict__ uw2,
        const float* __restrict__ iW1, const float* __restrict__ ib1,
        const float* __restrict__ iw2, const unsigned short* __restrict__ zb,
        float* __restrict__ wsum){
  __shared__ float sW[64*132];
  __shared__ float sA[64*36];
  __shared__ float sBias[128], sV[128];
  __shared__ float red[2];
  int tid = threadIdx.x, tx = tid & 15, ty = tid >> 4;
  int bid = blockIdx.x;
  const float *W1, *b1, *w2; const unsigned short* z; int nn, lb, wo;
  if (bid < NBU){ W1 = uW1; b1 = ub1; w2 = uw2; z = zb; nn = N_USERS; lb = bid; wo = 0; }
  else { W1 = iW1; b1 = ib1; w2 = iw2; z = zb + (long)2*N_USERS*DD;
         nn = N_ITEMS; lb = bid - NBU; wo = 2; }

  for (int i = tid; i < 2048; i += 256){
    int r = i >> 5, c = (i & 31) << 2;
    *(float4*)&sW[r*132 + c] = *(const float4*)&W1[r*128 + c];
  }
  if (tid < 128){ sBias[tid] = b1[tid]; sV[tid] = w2[tid]; }
  if (tid < 2) red[tid] = 0.f;

  for (int m = 0; m < 2; ++m){
    __syncthreads();
    {
      int r = tid & 31, q0 = tid >> 5;
      int rr = lb*ROWS + r;
      int rowg = (rr < nn ? rr : nn - 1) + m*nn;
      for (int q = q0; q < 16; q += 8){
        ushort4 v = *(const ushort4*)&z[(long)rowg*DD + 4*q];
        sA[(4*q+0)*36 + r] = b2f(v.x);
        sA[(4*q+1)*36 + r] = b2f(v.y);
        sA[(4*q+2)*36 + r] = b2f(v.z);
        sA[(4*q+3)*36 + r] = b2f(v.w);
      }
    }
    __syncthreads();

    float w[2][8];
    #pragma unroll
    for (int i = 0; i < 2; ++i)
      #pragma unroll
      for (int k = 0; k < 8; ++k) w[i][k] = sBias[8*tx + k];
    for (int d = 0; d < 64; ++d){
      float2 a = *(const float2*)&sA[d*36 + 2*ty];
      float4 b0 = *(const float4*)&sW[d*132 + 8*tx];
      float4 b4 = *(const float4*)&sW[d*132 + 8*tx + 4];
      float bb[8] = {b0.x,b0.y,b0.z,b0.w,b4.x,b4.y,b4.z,b4.w};
      #pragma unroll
      for (int k = 0; k < 8; ++k){ w[0][k] += a.x*bb[k]; w[1][k] += a.y*bb[k]; }
    }
    float part = 0.f;
    #pragma unroll
    for (int i = 0; i < 2; ++i){
      int rr = lb*ROWS + 2*ty + i;
      if (rr < nn){
        #pragma unroll
        for (int k = 0; k < 8; ++k) part += tanh_fast(w[i][k]) * sV[8*tx + k];
      }
    }
    part += __shfl_xor(part, 1, 64);
    part += __shfl_xor(part, 2, 64);
    part += __shfl_xor(part, 4, 64);
    part += __shfl_xor(part, 8, 64);
    part += __shfl_xor(part, 16, 64);
    part += __shfl_xor(part, 32, 64);
    if ((tid & 63) == 0) atomicAdd(&red[m], part);
  }
  __syncthreads();
  if (tid < 2) atomicAdd(&wsum[wo + tid], red[tid]);
}

__global__ void k_beta(const float* __restrict__ wsum, float* __restrict__ beta){
  if (threadIdx.x == 0 && blockIdx.x == 0){
    float u0 = wsum[0] / (float)N_USERS, u1 = wsum[1] / (float)N_USERS;
    float m = fmaxf(u0, u1);
    float e0 = __expf(u0 - m), e1 = __expf(u1 - m);
    beta[0] = e0/(e0+e1); beta[1] = e1/(e0+e1);
    float i0 = wsum[2] / (float)N_ITEMS, i1 = wsum[3] / (float)N_ITEMS;
    m = fmaxf(i0, i1);
    e0 = __expf(i0 - m); e1 = __expf(i1 - m);
    beta[2] = e0/(e0+e1); beta[3] = e1/(e0+e1);
  }
}

__global__ void k_final(const float* __restrict__ total, const unsigned short* __restrict__ zb,
                        const float* __restrict__ beta, float* __restrict__ out){
  int i = blockIdx.x*256 + threadIdx.x;
  if (i >= N_NODES*DD) return;
  float h;
  if (i < N_USERS*DD)
    h = beta[0]*b2f(zb[i]) + beta[1]*b2f(zb[N_USERS*DD + i]);
  else {
    int j = i - N_USERS*DD;
    h = beta[2]*b2f(zb[2*N_USERS*DD + j]) + beta[3]*b2f(zb[(2*N_USERS + N_ITEMS)*DD + j]);
  }
  out[i] = 0.5f*total[i] + 0.5f*h;
}

extern "C" void kernel_launch(void* const* d_in, const int* in_sizes, int n_in,
                              void* d_out, int out_size, void* d_ws, size_t ws_size,
                              hipStream_t stream) {
  const int*   G_idx = (const int*)d_in[0];
  const float* G_val = (const float*)d_in[1];
  const float* fu    = (const float*)d_in[2];
  const float* fi    = (const float*)d_in[3];
  const float* u_int = (const float*)d_in[4];
  const float* i_int = (const float*)d_in[5];
  const int*   mp_u  = (const int*)d_in[6];
  const int*   mp_i  = (const int*)d_in[7];
  const float* uW1   = (const float*)d_in[8];
  const float* ub1   = (const float*)d_in[9];
  const float* uw2   = (const float*)d_in[10];
  const float* iW1   = (const float*)d_in[11];
  const float* ib1   = (const float*)d_in[12];
  const float* iw2   = (const float*)d_in[13];
  float* out = (float*)d_out;

  float* ws = (float*)d_ws;
  // Phase A (G build + layers):
  float*        total  = ws;                                // [0, 9.6M)
  float*        cur    = ws + 9600000;                      // [9.6M, 19.2M)
  unsigned short* gnnh = (unsigned short*)(ws + 19200000);  // [19.2M, 24M) f16 9.6M elems
  unsigned short* curh = (unsigned short*)(ws + 24000000);  // [24M, 28.8M) f16 9.6M elems
  uint2*        kvG    = (uint2*)ws;                        // [0, 6.4M) dead before k_init
  unsigned int* packG  = (unsigned int*)(ws + 28800000);    // [28.8M, 32.0M)
  int*          offG   = (int*)(ws + 33700000);             // 150001
  int*          whG    = (int*)(ws + 34930000);             // 256*293 = 75008
  int*          colG   = (int*)(ws + 35018000);             // 293
  int*          bBG    = (int*)(ws + 35019000);             // 294
  // Phase B (HAN):
  unsigned int* keyH   = (unsigned int*)(ws + 9600000);     // [9.6M,14.4M) dead before zb
  unsigned short* zb   = (unsigned short*)(ws + 9600000);   // [9.6M,19.2M)
  unsigned short* fb   = (unsigned short*)(ws + 19200000);  // [19.2M,24M) 150K*64 bf16 (after gnnh dead)
  unsigned int* ssrcH  = (unsigned int*)(ws + 28800000);    // [28.8M,33.6M)
  int*          degoH  = (int*)(ws + 34000000);             // 300k
  int*          offH   = (int*)(ws + 34300000);             // 300001
  int*          whH    = (int*)(ws + 34610000);             // 256*586 = 150016
  int*          colH   = (int*)(ws + 35010000);             // 586
  int*          bBH    = (int*)(ws + 35012000);             // 587
  float*        wsum   = ws + 35030000;                     // 4
  float*        beta   = ws + 35030004;                     // 4

  hipMemsetAsync(wsum, 0, 4*sizeof(float), stream);
  hipMemsetAsync(degoH, 0, NH*sizeof(int), stream);

  // ---- G CSR build (atomic-free partition; before k_init: kvG aliases total/cur) ----
  k_h1_g<<<256, 256, 0, stream>>>(G_idx, whG);
  k_colscan<<<NBG, 256, 0, stream>>>(whG, NBG, colG);
  k_bscan<<<1, 256, 0, stream>>>(colG, NBG, E_G, bBG);
  k_h2_g<<<256, 256, 0, stream>>>(G_idx, G_val, whG, bBG, kvG);
  k_p2_g<<<NBG, 256, 0, stream>>>(bBG, kvG, offG, packG);

  k_init<<<(N_NODES*DD + 255)/256, 256, 0, stream>>>(fu, fi, cur, curh, total);

  // ---- DCCF layers (spmm gathers f16 curh, writes f16 gnnh; intent merged u+i) ----
  for (int layer = 0; layer < 2; ++layer){
    k_spmm_gp<<<(N_NODES + 3)/4, 256, 0, stream>>>(offG, packG, curh, gnnh);
    k_intent2<<<NBU + NBI, 256, 0, stream>>>(u_int, i_int, gnnh, cur, curh, total);
  }

  // ---- HAN build (atomic-free dst partition; dego via big-grid atomics) ----
  k_dego<<<2048, 256, 0, stream>>>(mp_u, mp_i, degoH);
  k_h1_h<<<256, 256, 0, stream>>>(mp_u, mp_i, whH);
  k_colscan<<<NBH, 256, 0, stream>>>(whH, NBH, colH);
  k_bscan<<<1, 256, 0, stream>>>(colH, NBH, E_HAN, bBH);
  k_h2_h<<<256, 256, 0, stream>>>(mp_u, mp_i, whH, bBH, keyH);
  k_fb<<<(N_NODES*DD + 255)/256, 256, 0, stream>>>(fu, fi, fb);
  k_p2_h<<<NBH, 256, 0, stream>>>(bBH, keyH, degoH, offH, ssrcH);
  k_han_gb<<<(NH + 3)/4, 256, 0, stream>>>(offH, ssrcH, fb, zb);

  // ---- semantic attention (merged u+i) + combine ----
  k_sem2<<<NBU + NBI, 256, 0, stream>>>(uW1, ub1, uw2, iW1, ib1, iw2, zb, wsum);
  k_beta<<<1, 64, 0, stream>>>(wsum, beta);
  k_final<<<(N_NODES*DD + 255)/256, 256, 0, stream>>>(total, zb, beta, out);
}

// Round 6
// 1141.029 us; speedup vs baseline: 1.1302x; 1.1302x over previous
//
#include <hip/hip_runtime.h>
#include <hip/hip_bf16.h>
#include <hip/hip_fp16.h>
#include <math.h>

#define N_USERS 100000
#define N_ITEMS 50000
#define N_NODES 150000
#define DD 64
#define E_G 3200000
#define EU 1600000
#define EI 800000
#define E_HAN 4800000
#define NH 300000
#define NBG 293        // ceil(150000/512)
#define NBH 586        // ceil(300000/512)
#define ROWS 32
#define NBU 3125       // ceil(100000/32)
#define NBI 1563       // ceil(50000/32)

typedef float v2f __attribute__((ext_vector_type(2)));

__device__ __forceinline__ float invdeg(float d){
  return d > 0.f ? rsqrtf(fmaxf(d, 1e-12f)) : 0.f;
}
__device__ __forceinline__ float tanh_fast(float x){
  float cx = fminf(15.f, fmaxf(-15.f, x));
  float t = __expf(2.f*cx);
  return (t - 1.f)/(t + 1.f);
}
__device__ __forceinline__ unsigned short f2b(float x){
  unsigned int b = __float_as_uint(x);
  b += 0x7FFFu + ((b >> 16) & 1u);
  return (unsigned short)(b >> 16);
}
__device__ __forceinline__ float b2f(unsigned short u){
  return __uint_as_float(((unsigned int)u) << 16);
}
// unpack 2 bf16 (lo,hi) from one uint into a float2 vector (pk_fma friendly)
__device__ __forceinline__ v2f b2f2(unsigned int u){
  v2f r;
  r.x = __uint_as_float(u << 16);
  r.y = __uint_as_float(u & 0xFFFF0000u);
  return r;
}
__device__ __forceinline__ unsigned short f2h(float x){
  return __half_as_ushort(__float2half(x));
}
__device__ __forceinline__ float h2f(unsigned short u){
  return __half2float(__ushort_as_half(u));
}
__device__ __forceinline__ v2f h2v2(unsigned int u){
  __half2 h = *reinterpret_cast<__half2*>(&u);
  float2 t = __half22float2(h);
  v2f r; r.x = t.x; r.y = t.y;
  return r;
}

__global__ void k_init(const float* __restrict__ fu, const float* __restrict__ fi,
                       float* __restrict__ cur, unsigned short* __restrict__ curh,
                       float* __restrict__ total){
  int i = blockIdx.x*256 + threadIdx.x;
  if (i >= N_NODES*DD) return;
  float v = (i < N_USERS*DD) ? fu[i] : fi[i - N_USERS*DD];
  cur[i] = v; total[i] = v; curh[i] = f2h(v);
}

// ---------------- generic scan helpers ----------------
__global__ __launch_bounds__(256) void k_colscan(int* __restrict__ wh, int nb,
                                                 int* __restrict__ colsum){
  __shared__ int s[256];
  int b = blockIdx.x, tid = threadIdx.x;
  int v = wh[tid*nb + b];
  s[tid] = v; __syncthreads();
  for (int o = 1; o < 256; o <<= 1){
    int t = (tid >= o) ? s[tid - o] : 0;
    __syncthreads();
    s[tid] += t;
    __syncthreads();
  }
  wh[tid*nb + b] = s[tid] - v;
  if (tid == 255) colsum[b] = s[255];
}

__global__ __launch_bounds__(256) void k_bscan(const int* __restrict__ colsum, int nb,
                                               int total, int* __restrict__ bB){
  __shared__ int s[256];
  __shared__ int carry;
  int tid = threadIdx.x;
  if (tid == 0) carry = 0;
  __syncthreads();
  for (int base = 0; base < nb; base += 256){
    int i = base + tid;
    int v = (i < nb) ? colsum[i] : 0;
    s[tid] = v; __syncthreads();
    for (int o = 1; o < 256; o <<= 1){
      int t = (tid >= o) ? s[tid - o] : 0;
      __syncthreads();
      s[tid] += t;
      __syncthreads();
    }
    int c = carry;
    if (i < nb) bB[i] = c + s[tid] - v;
    __syncthreads();
    if (tid == 255) carry = c + s[255];
    __syncthreads();
  }
  if (tid == 0) bB[nb] = total;
}

// ---------------- G build ----------------
__global__ __launch_bounds__(256) void k_h1_g(const int* __restrict__ gi,
                                              int* __restrict__ wh){
  __shared__ int h[NBG];
  int tid = threadIdx.x;
  for (int b = tid; b < NBG; b += 256) h[b] = 0;
  __syncthreads();
  int e0 = blockIdx.x*(E_G/256);
  for (int i = tid; i < E_G/256; i += 256)
    atomicAdd(&h[gi[e0 + i] >> 9], 1);
  __syncthreads();
  for (int b = tid; b < NBG; b += 256) wh[blockIdx.x*NBG + b] = h[b];
}

__global__ __launch_bounds__(256) void k_h2_g(const int* __restrict__ gi,
        const float* __restrict__ gv, const int* __restrict__ wh,
        const int* __restrict__ bB, uint2* __restrict__ kv){
  __shared__ int lcur[NBG];
  int tid = threadIdx.x, wg = blockIdx.x;
  for (int b = tid; b < NBG; b += 256) lcur[b] = bB[b] + wh[wg*NBG + b];
  __syncthreads();
  int e0 = wg*(E_G/256);
  for (int i = tid; i < E_G/256; i += 256){
    int e = e0 + i;
    int d = gi[e];
    int p = atomicAdd(&lcur[d >> 9], 1);
    uint2 r;
    r.x = ((unsigned)(d & 511) << 18) | (unsigned)gi[E_G + e];
    r.y = __float_as_uint(gv[e]);
    kv[p] = r;
  }
}

__global__ __launch_bounds__(256) void k_p2_g(const int* __restrict__ bB,
        const uint2* __restrict__ kv, int* __restrict__ off,
        unsigned int* __restrict__ packed){
  __shared__ int cnt[512], sc[512], lcur[512];
  int b = blockIdx.x, tid = threadIdx.x;
  int d0 = b << 9;
  int dcnt = min(512, N_NODES - d0);
  int pb = bB[b], pe = bB[b+1];
  for (int i = tid; i < 512; i += 256) cnt[i] = 0;
  __syncthreads();
  for (int p = pb + tid; p < pe; p += 256)
    atomicAdd(&cnt[kv[p].x >> 18], 1);
  __syncthreads();
  sc[tid] = cnt[tid]; sc[tid + 256] = cnt[tid + 256];
  __syncthreads();
  for (int o = 1; o < 512; o <<= 1){
    int a0 = (tid >= o) ? sc[tid - o] : 0;
    int a1 = sc[tid + 256 - o];
    __syncthreads();
    sc[tid] += a0; sc[tid + 256] += a1;
    __syncthreads();
  }
  for (int i = tid; i < 512; i += 256) lcur[i] = pb + sc[i] - cnt[i];
  for (int i = tid; i < dcnt; i += 256) off[d0 + i] = pb + sc[i] - cnt[i];
  if (tid == 0) off[d0 + dcnt] = pe;
  __syncthreads();
  for (int p = pb + tid; p < pe; p += 256){
    uint2 r = kv[p];
    int dl = (int)(r.x >> 18);
    unsigned int s = r.x & 0x3FFFFu;
    float v = __uint_as_float(r.y);
    int q14 = (int)(v*16383.f + 0.5f);
    if (q14 > 16383) q14 = 16383;
    int q = atomicAdd(&lcur[dl], 1);
    packed[q] = (s << 14) | (unsigned int)q14;
  }
}

// ---------------- DCCF spmm gather (packed CSR, f16 table, 2 gathers in flight) ----
__global__ __launch_bounds__(256) void k_spmm_gp(const int* __restrict__ off,
        const unsigned int* __restrict__ packed,
        const unsigned short* __restrict__ curh, unsigned short* __restrict__ gnnh){
  int wv = threadIdx.x >> 6, lane = threadIdx.x & 63;
  int node = blockIdx.x*4 + wv;
  if (node >= N_NODES) return;
  int b = off[node], e = off[node+1];
  int c8 = (lane & 7)*8, sl = lane >> 3;
  const float inv14 = 1.f/16383.f;
  v2f a0 = {0.f,0.f}, a1 = {0.f,0.f}, a2 = {0.f,0.f}, a3 = {0.f,0.f};
  for (int k = b; k < e; k += 16){
    int i0 = k + sl, i1 = i0 + 8;
    unsigned int pk0 = (i0 < e) ? packed[i0] : 0u;   // pk==0 -> weight 0
    unsigned int pk1 = (i1 < e) ? packed[i1] : 0u;
    int s0 = (int)(pk0 >> 14), s1 = (int)(pk1 >> 14);
    float w0 = (float)(pk0 & 16383u) * inv14;
    float w1 = (float)(pk1 & 16383u) * inv14;
    const uint4 u0 = *(const uint4*)&curh[s0*DD + c8];
    const uint4 u1 = *(const uint4*)&curh[s1*DD + c8];
    a0 += w0 * h2v2(u0.x); a1 += w0 * h2v2(u0.y);
    a2 += w0 * h2v2(u0.z); a3 += w0 * h2v2(u0.w);
    a0 += w1 * h2v2(u1.x); a1 += w1 * h2v2(u1.y);
    a2 += w1 * h2v2(u1.z); a3 += w1 * h2v2(u1.w);
  }
  float a[8] = {a0.x,a0.y,a1.x,a1.y,a2.x,a2.y,a3.x,a3.y};
  #pragma unroll
  for (int j = 0; j < 8; ++j){
    a[j] += __shfl_xor(a[j], 8, 64);
    a[j] += __shfl_xor(a[j], 16, 64);
    a[j] += __shfl_xor(a[j], 32, 64);
  }
  if (lane < 8){
    uint4 o;
    o.x = (unsigned)f2h(a[0]) | ((unsigned)f2h(a[1]) << 16);
    o.y = (unsigned)f2h(a[2]) | ((unsigned)f2h(a[3]) << 16);
    o.z = (unsigned)f2h(a[4]) | ((unsigned)f2h(a[5]) << 16);
    o.w = (unsigned)f2h(a[6]) | ((unsigned)f2h(a[7]) << 16);
    *(uint4*)&gnnh[node*DD + c8] = o;
  }
}

// ---------------- intent (tiled GEMM, user+item merged) ----------------
__global__ __launch_bounds__(256) void k_intent2(const float* __restrict__ u_int,
        const float* __restrict__ i_int,
        const unsigned short* __restrict__ gnnh, float* __restrict__ cur,
        unsigned short* __restrict__ curh, float* __restrict__ total){
  __shared__ float sB[64*132];
  __shared__ float sU[ROWS*132];
  int tid = threadIdx.x, tx = tid & 15, ty = tid >> 4;
  int bid = blockIdx.x;
  const float* intent; int base, nrows, lb;
  if (bid < NBU){ intent = u_int; base = 0; nrows = N_USERS; lb = bid; }
  else          { intent = i_int; base = N_USERS; nrows = N_ITEMS; lb = bid - NBU; }

  for (int i = tid; i < 2048; i += 256){
    int r = i >> 5, c = (i & 31) << 2;
    *(float4*)&sB[r*132 + c] = *(const float4*)&intent[r*128 + c];
  }
  {
    int r = tid & 31, q0 = tid >> 5;
    int rr = lb*ROWS + r;
    int rowg = base + (rr < nrows ? rr : nrows - 1);
    for (int q = q0; q < 16; q += 8){
      float4 v = *(const float4*)&cur[rowg*DD + 4*q];
      sU[(4*q+0)*36 + r] = v.x;
      sU[(4*q+1)*36 + r] = v.y;
      sU[(4*q+2)*36 + r] = v.z;
      sU[(4*q+3)*36 + r] = v.w;
    }
  }
  __syncthreads();

  float w[2][8];
  #pragma unroll
  for (int i = 0; i < 2; ++i)
    #pragma unroll
    for (int k = 0; k < 8; ++k) w[i][k] = 0.f;
  for (int d = 0; d < 64; ++d){
    float2 a = *(const float2*)&sU[d*36 + 2*ty];
    float4 b0 = *(const float4*)&sB[d*132 + 8*tx];
    float4 b1 = *(const float4*)&sB[d*132 + 8*tx + 4];
    float bb[8] = {b0.x,b0.y,b0.z,b0.w,b1.x,b1.y,b1.z,b1.w};
    #pragma unroll
    for (int k = 0; k < 8; ++k){ w[0][k] += a.x*bb[k]; w[1][k] += a.y*bb[k]; }
  }

  float p[2][8];
  #pragma unroll
  for (int i = 0; i < 2; ++i){
    float mx = w[i][0];
    #pragma unroll
    for (int k = 1; k < 8; ++k) mx = fmaxf(mx, w[i][k]);
    mx = fmaxf(mx, __shfl_xor(mx, 1, 64));
    mx = fmaxf(mx, __shfl_xor(mx, 2, 64));
    mx = fmaxf(mx, __shfl_xor(mx, 4, 64));
    mx = fmaxf(mx, __shfl_xor(mx, 8, 64));
    float s = 0.f;
    #pragma unroll
    for (int k = 0; k < 8; ++k){ p[i][k] = __expf(w[i][k] - mx); s += p[i][k]; }
    s += __shfl_xor(s, 1, 64);
    s += __shfl_xor(s, 2, 64);
    s += __shfl_xor(s, 4, 64);
    s += __shfl_xor(s, 8, 64);
    float inv = 1.f / s;
    #pragma unroll
    for (int k = 0; k < 8; ++k) p[i][k] *= inv;
  }
  __syncthreads();
  #pragma unroll
  for (int i = 0; i < 2; ++i){
    *(float4*)&sU[(2*ty+i)*132 + 8*tx]     = make_float4(p[i][0],p[i][1],p[i][2],p[i][3]);
    *(float4*)&sU[(2*ty+i)*132 + 8*tx + 4] = make_float4(p[i][4],p[i][5],p[i][6],p[i][7]);
  }
  __syncthreads();

  float o[2][4];
  #pragma unroll
  for (int i = 0; i < 2; ++i)
    #pragma unroll
    for (int m = 0; m < 4; ++m) o[i][m] = 0.f;
  for (int q = 0; q < 32; ++q){
    float4 p0 = *(const float4*)&sU[(2*ty+0)*132 + 4*q];
    float4 p1 = *(const float4*)&sU[(2*ty+1)*132 + 4*q];
    #pragma unroll
    for (int m = 0; m < 4; ++m){
      float4 bl = *(const float4*)&sB[(4*tx+m)*132 + 4*q];
      o[0][m] += p0.x*bl.x + p0.y*bl.y + p0.z*bl.z + p0.w*bl.w;
      o[1][m] += p1.x*bl.x + p1.y*bl.y + p1.z*bl.z + p1.w*bl.w;
    }
  }

  #pragma unroll
  for (int i = 0; i < 2; ++i){
    int rr = lb*ROWS + 2*ty + i;
    if (rr < nrows){
      int rowg = base + rr;
      ushort4 gh = *(const ushort4*)&gnnh[rowg*DD + 4*tx];
      float4 c = *(const float4*)&cur[rowg*DD + 4*tx];
      float4 t = *(const float4*)&total[rowg*DD + 4*tx];
      float4 cn = make_float4(h2f(gh.x) + o[i][0] + c.x, h2f(gh.y) + o[i][1] + c.y,
                              h2f(gh.z) + o[i][2] + c.z, h2f(gh.w) + o[i][3] + c.w);
      *(float4*)&cur[rowg*DD + 4*tx] = cn;
      ushort4 ch;
      ch.x = f2h(cn.x); ch.y = f2h(cn.y); ch.z = f2h(cn.z); ch.w = f2h(cn.w);
      *(ushort4*)&curh[rowg*DD + 4*tx] = ch;
      *(float4*)&total[rowg*DD + 4*tx] =
          make_float4(t.x + cn.x, t.y + cn.y, t.z + cn.z, t.w + cn.w);
    }
  }
}

// ---------------- HAN build ----------------
__device__ __forceinline__ void han_decode(int t, const int* mp_u, const int* mp_i,
                                           int* gs, int* gd){
  if (t < 2*EU){
    int s = (t < EU) ? 0 : 1;
    int e = t - s*EU;
    const int* sp = mp_u + (long)s*2*EU;
    int nb = s*N_USERS;
    *gs = nb + sp[e]; *gd = nb + sp[EU + e];
  } else {
    int t2 = t - 2*EU;
    int s = (t2 < EI) ? 0 : 1;
    int e = t2 - s*EI;
    const int* sp = mp_i + (long)s*2*EI;
    int nb = 2*N_USERS + s*N_ITEMS;
    *gs = nb + sp[e]; *gd = nb + sp[EI + e];
  }
}

// dst-bucket + src-bucket histograms (per-wg, LDS)
__global__ __launch_bounds__(256) void k_h1_h(const int* __restrict__ mp_u,
        const int* __restrict__ mp_i, int* __restrict__ whD, int* __restrict__ whS){
  __shared__ int hd[NBH], hs[NBH];
  int tid = threadIdx.x;
  for (int b = tid; b < NBH; b += 256){ hd[b] = 0; hs[b] = 0; }
  __syncthreads();
  int t0 = blockIdx.x*(E_HAN/256);
  for (int i = tid; i < E_HAN/256; i += 256){
    int gs, gd;
    han_decode(t0 + i, mp_u, mp_i, &gs, &gd);
    atomicAdd(&hd[gd >> 9], 1);
    atomicAdd(&hs[gs >> 9], 1);
  }
  __syncthreads();
  for (int b = tid; b < NBH; b += 256){
    whD[blockIdx.x*NBH + b] = hd[b];
    whS[blockIdx.x*NBH + b] = hs[b];
  }
}

__global__ __launch_bounds__(256) void k_h2_h(const int* __restrict__ mp_u,
        const int* __restrict__ mp_i, const int* __restrict__ whD,
        const int* __restrict__ whS, const int* __restrict__ bBD,
        const int* __restrict__ bBS, unsigned int* __restrict__ keyD,
        unsigned short* __restrict__ keyS){
  __shared__ int lcD[NBH], lcS[NBH];
  int tid = threadIdx.x, wg = blockIdx.x;
  for (int b = tid; b < NBH; b += 256){
    lcD[b] = bBD[b] + whD[wg*NBH + b];
    lcS[b] = bBS[b] + whS[wg*NBH + b];
  }
  __syncthreads();
  int t0 = wg*(E_HAN/256);
  for (int i = tid; i < E_HAN/256; i += 256){
    int gs, gd;
    han_decode(t0 + i, mp_u, mp_i, &gs, &gd);
    int pD = atomicAdd(&lcD[gd >> 9], 1);
    keyD[pD] = ((unsigned)(gd & 511) << 19) | (unsigned)gs;
    int pS = atomicAdd(&lcS[gs >> 9], 1);
    keyS[pS] = (unsigned short)(gs & 511);   // within-bucket index only
  }
}

// per-bucket LDS count of bucket-sorted ushort keys -> src out-degrees
__global__ __launch_bounds__(256) void k_cnt_hs(const int* __restrict__ bB,
        const unsigned short* __restrict__ keyS, int* __restrict__ dego){
  __shared__ int cnt[512];
  int b = blockIdx.x, tid = threadIdx.x;
  int d0 = b << 9;
  int dcnt = min(512, NH - d0);
  int pb = bB[b], pe = bB[b+1];
  for (int i = tid; i < 512; i += 256) cnt[i] = 0;
  __syncthreads();
  for (int p = pb + tid; p < pe; p += 256)
    atomicAdd(&cnt[keyS[p]], 1);
  __syncthreads();
  for (int i = tid; i < dcnt; i += 256) dego[d0 + i] = cnt[i];
}

// partition keyD by dst; pack ssrc = (feat_row(src) << 14) | q14(invdeg(degout[src]))
__global__ __launch_bounds__(256) void k_p2_h(const int* __restrict__ bB,
        const unsigned int* __restrict__ key, const int* __restrict__ dego,
        int* __restrict__ off, unsigned int* __restrict__ ssrc){
  __shared__ int cnt[512], sc[512], lcur[512];
  int b = blockIdx.x, tid = threadIdx.x;
  int d0 = b << 9;
  int dcnt = min(512, NH - d0);
  int pb = bB[b], pe = bB[b+1];
  for (int i = tid; i < 512; i += 256) cnt[i] = 0;
  __syncthreads();
  for (int p = pb + tid; p < pe; p += 256)
    atomicAdd(&cnt[key[p] >> 19], 1);
  __syncthreads();
  sc[tid] = cnt[tid]; sc[tid + 256] = cnt[tid + 256];
  __syncthreads();
  for (int o = 1; o < 512; o <<= 1){
    int a0 = (tid >= o) ? sc[tid - o] : 0;
    int a1 = sc[tid + 256 - o];
    __syncthreads();
    sc[tid] += a0; sc[tid + 256] += a1;
    __syncthreads();
  }
  for (int i = tid; i < 512; i += 256) lcur[i] = pb + sc[i] - cnt[i];
  for (int i = tid; i < dcnt; i += 256) off[d0 + i] = pb + sc[i] - cnt[i];
  if (tid == 0) off[d0 + dcnt] = pe;
  __syncthreads();
  for (int p = pb + tid; p < pe; p += 256){
    unsigned int k = key[p];
    int dl = (int)(k >> 19);
    int gs = (int)(k & 0x7FFFFu);
    // map HAN node id -> shared feature row [0,150000)
    int fsrc = gs - (gs >= N_USERS ? N_USERS : 0) - (gs >= 250000 ? 50000 : 0);
    float w = invdeg((float)dego[gs]);
    int q14 = (int)(w*16383.f + 0.5f);
    if (q14 > 16383) q14 = 16383;
    int q = atomicAdd(&lcur[dl], 1);
    ssrc[q] = ((unsigned)fsrc << 14) | (unsigned)q14;
  }
}

// fb[row] = bf16(feat[row]) for the shared 150K-row feature table
__global__ void k_fb(const float* __restrict__ fu, const float* __restrict__ fi,
                     unsigned short* __restrict__ fb){
  int i = blockIdx.x*256 + threadIdx.x;
  if (i >= N_NODES*DD) return;
  float f = (i < N_USERS*DD) ? fu[i] : fi[i - N_USERS*DD];
  fb[i] = f2b(f);
}

// z[g] (bf16) = invdeg(deg_in[g]) * sum q14(invdeg_out[src]) * fb[src]
// 8 lanes/edge x 16B loads, 16 edges per iteration, 2 gathers in flight/lane
__global__ __launch_bounds__(256) void k_han_gb(const int* __restrict__ off,
        const unsigned int* __restrict__ ssrc, const unsigned short* __restrict__ fb,
        unsigned short* __restrict__ zb){
  int wv = threadIdx.x >> 6, lane = threadIdx.x & 63;
  int g = blockIdx.x*4 + wv;
  if (g >= NH) return;
  int b = off[g], e = off[g+1];
  int c8 = (lane & 7)*8, sl = lane >> 3;
  const float inv14 = 1.f/16383.f;
  v2f a0 = {0.f,0.f}, a1 = {0.f,0.f}, a2 = {0.f,0.f}, a3 = {0.f,0.f};
  for (int k = b; k < e; k += 16){
    int i0 = k + sl, i1 = i0 + 8;
    unsigned int pk0 = (i0 < e) ? ssrc[i0] : 0u;   // pk==0 -> weight 0
    unsigned int pk1 = (i1 < e) ? ssrc[i1] : 0u;
    int s0 = (int)(pk0 >> 14), s1 = (int)(pk1 >> 14);
    float w0 = (float)(pk0 & 16383u) * inv14;
    float w1 = (float)(pk1 & 16383u) * inv14;
    const uint4 u0 = *(const uint4*)&fb[s0*DD + c8];
    const uint4 u1 = *(const uint4*)&fb[s1*DD + c8];
    a0 += w0 * b2f2(u0.x); a1 += w0 * b2f2(u0.y);
    a2 += w0 * b2f2(u0.z); a3 += w0 * b2f2(u0.w);
    a0 += w1 * b2f2(u1.x); a1 += w1 * b2f2(u1.y);
    a2 += w1 * b2f2(u1.z); a3 += w1 * b2f2(u1.w);
  }
  float a[8] = {a0.x,a0.y,a1.x,a1.y,a2.x,a2.y,a3.x,a3.y};
  #pragma unroll
  for (int j = 0; j < 8; ++j){
    a[j] += __shfl_xor(a[j], 8, 64);
    a[j] += __shfl_xor(a[j], 16, 64);
    a[j] += __shfl_xor(a[j], 32, 64);
  }
  if (lane < 8){
    float win = invdeg((float)(e - b));
    uint4 o;
    o.x = (unsigned)f2b(win*a[0]) | ((unsigned)f2b(win*a[1]) << 16);
    o.y = (unsigned)f2b(win*a[2]) | ((unsigned)f2b(win*a[3]) << 16);
    o.z = (unsigned)f2b(win*a[4]) | ((unsigned)f2b(win*a[5]) << 16);
    o.w = (unsigned)f2b(win*a[6]) | ((unsigned)f2b(win*a[7]) << 16);
    *(uint4*)&zb[g*DD + c8] = o;
  }
}

// semantic attention reduction (bf16 z input), user+item merged
__global__ __launch_bounds__(256) void k_sem2(const float* __restrict__ uW1,
        const float* __restrict__ ub1, const float* __restrict__ uw2,
        const float* __restrict__ iW1, const float* __restrict__ ib1,
        const float* __restrict__ iw2, const unsigned short* __restrict__ zb,
        float* __restrict__ wsum){
  __shared__ float sW[64*132];
  __shared__ float sA[64*36];
  __shared__ float sBias[128], sV[128];
  __shared__ float red[2];
  int tid = threadIdx.x, tx = tid & 15, ty = tid >> 4;
  int bid = blockIdx.x;
  const float *W1, *b1, *w2; const unsigned short* z; int nn, lb, wo;
  if (bid < NBU){ W1 = uW1; b1 = ub1; w2 = uw2; z = zb; nn = N_USERS; lb = bid; wo = 0; }
  else { W1 = iW1; b1 = ib1; w2 = iw2; z = zb + (long)2*N_USERS*DD;
         nn = N_ITEMS; lb = bid - NBU; wo = 2; }

  for (int i = tid; i < 2048; i += 256){
    int r = i >> 5, c = (i & 31) << 2;
    *(float4*)&sW[r*132 + c] = *(const float4*)&W1[r*128 + c];
  }
  if (tid < 128){ sBias[tid] = b1[tid]; sV[tid] = w2[tid]; }
  if (tid < 2) red[tid] = 0.f;

  for (int m = 0; m < 2; ++m){
    __syncthreads();
    {
      int r = tid & 31, q0 = tid >> 5;
      int rr = lb*ROWS + r;
      int rowg = (rr < nn ? rr : nn - 1) + m*nn;
      for (int q = q0; q < 16; q += 8){
        ushort4 v = *(const ushort4*)&z[(long)rowg*DD + 4*q];
        sA[(4*q+0)*36 + r] = b2f(v.x);
        sA[(4*q+1)*36 + r] = b2f(v.y);
        sA[(4*q+2)*36 + r] = b2f(v.z);
        sA[(4*q+3)*36 + r] = b2f(v.w);
      }
    }
    __syncthreads();

    float w[2][8];
    #pragma unroll
    for (int i = 0; i < 2; ++i)
      #pragma unroll
      for (int k = 0; k < 8; ++k) w[i][k] = sBias[8*tx + k];
    for (int d = 0; d < 64; ++d){
      float2 a = *(const float2*)&sA[d*36 + 2*ty];
      float4 b0 = *(const float4*)&sW[d*132 + 8*tx];
      float4 b4 = *(const float4*)&sW[d*132 + 8*tx + 4];
      float bb[8] = {b0.x,b0.y,b0.z,b0.w,b4.x,b4.y,b4.z,b4.w};
      #pragma unroll
      for (int k = 0; k < 8; ++k){ w[0][k] += a.x*bb[k]; w[1][k] += a.y*bb[k]; }
    }
    float part = 0.f;
    #pragma unroll
    for (int i = 0; i < 2; ++i){
      int rr = lb*ROWS + 2*ty + i;
      if (rr < nn){
        #pragma unroll
        for (int k = 0; k < 8; ++k) part += tanh_fast(w[i][k]) * sV[8*tx + k];
      }
    }
    part += __shfl_xor(part, 1, 64);
    part += __shfl_xor(part, 2, 64);
    part += __shfl_xor(part, 4, 64);
    part += __shfl_xor(part, 8, 64);
    part += __shfl_xor(part, 16, 64);
    part += __shfl_xor(part, 32, 64);
    if ((tid & 63) == 0) atomicAdd(&red[m], part);
  }
  __syncthreads();
  if (tid < 2) atomicAdd(&wsum[wo + tid], red[tid]);
}

__global__ void k_beta(const float* __restrict__ wsum, float* __restrict__ beta){
  if (threadIdx.x == 0 && blockIdx.x == 0){
    float u0 = wsum[0] / (float)N_USERS, u1 = wsum[1] / (float)N_USERS;
    float m = fmaxf(u0, u1);
    float e0 = __expf(u0 - m), e1 = __expf(u1 - m);
    beta[0] = e0/(e0+e1); beta[1] = e1/(e0+e1);
    float i0 = wsum[2] / (float)N_ITEMS, i1 = wsum[3] / (float)N_ITEMS;
    m = fmaxf(i0, i1);
    e0 = __expf(i0 - m); e1 = __expf(i1 - m);
    beta[2] = e0/(e0+e1); beta[3] = e1/(e0+e1);
  }
}

__global__ void k_final(const float* __restrict__ total, const unsigned short* __restrict__ zb,
                        const float* __restrict__ beta, float* __restrict__ out){
  int i = blockIdx.x*256 + threadIdx.x;
  if (i >= N_NODES*DD) return;
  float h;
  if (i < N_USERS*DD)
    h = beta[0]*b2f(zb[i]) + beta[1]*b2f(zb[N_USERS*DD + i]);
  else {
    int j = i - N_USERS*DD;
    h = beta[2]*b2f(zb[2*N_USERS*DD + j]) + beta[3]*b2f(zb[(2*N_USERS + N_ITEMS)*DD + j]);
  }
  out[i] = 0.5f*total[i] + 0.5f*h;
}

extern "C" void kernel_launch(void* const* d_in, const int* in_sizes, int n_in,
                              void* d_out, int out_size, void* d_ws, size_t ws_size,
                              hipStream_t stream) {
  const int*   G_idx = (const int*)d_in[0];
  const float* G_val = (const float*)d_in[1];
  const float* fu    = (const float*)d_in[2];
  const float* fi    = (const float*)d_in[3];
  const float* u_int = (const float*)d_in[4];
  const float* i_int = (const float*)d_in[5];
  const int*   mp_u  = (const int*)d_in[6];
  const int*   mp_i  = (const int*)d_in[7];
  const float* uW1   = (const float*)d_in[8];
  const float* ub1   = (const float*)d_in[9];
  const float* uw2   = (const float*)d_in[10];
  const float* iW1   = (const float*)d_in[11];
  const float* ib1   = (const float*)d_in[12];
  const float* iw2   = (const float*)d_in[13];
  float* out = (float*)d_out;

  float* ws = (float*)d_ws;
  // Phase A (G build + layers):
  float*        total  = ws;                                // [0, 9.6M)
  float*        cur    = ws + 9600000;                      // [9.6M, 19.2M)
  unsigned short* gnnh = (unsigned short*)(ws + 19200000);  // [19.2M, 24M) f16 9.6M elems
  unsigned short* curh = (unsigned short*)(ws + 24000000);  // [24M, 28.8M) f16 9.6M elems
  uint2*        kvG    = (uint2*)ws;                        // [0, 6.4M) dead before k_init
  unsigned int* packG  = (unsigned int*)(ws + 28800000);    // [28.8M, 32.0M)
  int*          offG   = (int*)(ws + 33700000);             // 150001
  int*          whG    = (int*)(ws + 34930000);             // 256*293 = 75008
  int*          colG   = (int*)(ws + 35018000);             // 293
  int*          bBG    = (int*)(ws + 35019000);             // 294
  // Phase B (HAN):
  unsigned int* keyH   = (unsigned int*)(ws + 9600000);     // [9.6M,14.4M) dead before zb
  unsigned short* zb   = (unsigned short*)(ws + 9600000);   // [9.6M,19.2M)
  unsigned short* keyS = (unsigned short*)(ws + 19200000);  // [19.2M,21.6M) 4.8M ushort, dead before fb
  unsigned short* fb   = (unsigned short*)(ws + 19200000);  // [19.2M,24M) 150K*64 bf16
  unsigned int* ssrcH  = (unsigned int*)(ws + 28800000);    // [28.8M,33.6M)
  int*          degoH  = (int*)(ws + 34000000);             // 300k
  int*          offH   = (int*)(ws + 34300000);             // 300001
  int*          whH    = (int*)(ws + 34610000);             // 256*586 = 150016
  int*          whS    = (int*)(ws + 34770000);             // 150016
  int*          colH   = (int*)(ws + 35010000);             // 586
  int*          bBH    = (int*)(ws + 35012000);             // 587
  int*          colS   = (int*)(ws + 35014000);             // 586
  int*          bBS    = (int*)(ws + 35016000);             // 587
  float*        wsum   = ws + 35030000;                     // 4
  float*        beta   = ws + 35030004;                     // 4

  hipMemsetAsync(wsum, 0, 4*sizeof(float), stream);

  // ---- G CSR build (atomic-free partition; before k_init: kvG aliases total/cur) ----
  k_h1_g<<<256, 256, 0, stream>>>(G_idx, whG);
  k_colscan<<<NBG, 256, 0, stream>>>(whG, NBG, colG);
  k_bscan<<<1, 256, 0, stream>>>(colG, NBG, E_G, bBG);
  k_h2_g<<<256, 256, 0, stream>>>(G_idx, G_val, whG, bBG, kvG);
  k_p2_g<<<NBG, 256, 0, stream>>>(bBG, kvG, offG, packG);

  k_init<<<(N_NODES*DD + 255)/256, 256, 0, stream>>>(fu, fi, cur, curh, total);

  // ---- DCCF layers (spmm gathers f16 curh, writes f16 gnnh; intent merged u+i) ----
  for (int layer = 0; layer < 2; ++layer){
    k_spmm_gp<<<(N_NODES + 3)/4, 256, 0, stream>>>(offG, packG, curh, gnnh);
    k_intent2<<<NBU + NBI, 256, 0, stream>>>(u_int, i_int, gnnh, cur, curh, total);
  }

  // ---- HAN build (atomic-free partition; dego via bucket-sorted LDS count) ----
  k_h1_h<<<256, 256, 0, stream>>>(mp_u, mp_i, whH, whS);
  k_colscan<<<NBH, 256, 0, stream>>>(whH, NBH, colH);
  k_bscan<<<1, 256, 0, stream>>>(colH, NBH, E_HAN, bBH);
  k_colscan<<<NBH, 256, 0, stream>>>(whS, NBH, colS);
  k_bscan<<<1, 256, 0, stream>>>(colS, NBH, E_HAN, bBS);
  k_h2_h<<<256, 256, 0, stream>>>(mp_u, mp_i, whH, whS, bBH, bBS, keyH, keyS);
  k_cnt_hs<<<NBH, 256, 0, stream>>>(bBS, keyS, degoH);   // consumes keyS (before fb write)
  k_fb<<<(N_NODES*DD + 255)/256, 256, 0, stream>>>(fu, fi, fb);
  k_p2_h<<<NBH, 256, 0, stream>>>(bBH, keyH, degoH, offH, ssrcH);
  k_han_gb<<<(NH + 3)/4, 256, 0, stream>>>(offH, ssrcH, fb, zb);

  // ---- semantic attention (merged u+i) + combine ----
  k_sem2<<<NBU + NBI, 256, 0, stream>>>(uW1, ub1, uw2, iW1, ib1, iw2, zb, wsum);
  k_beta<<<1, 64, 0, stream>>>(wsum, beta);
  k_final<<<(N_NODES*DD + 255)/256, 256, 0, stream>>>(total, zb, beta, out);
}

// Round 7
// 1038.640 us; speedup vs baseline: 1.2416x; 1.0986x over previous
//
#include <hip/hip_runtime.h>
#include <hip/hip_bf16.h>
#include <hip/hip_fp16.h>
#include <math.h>

#define N_USERS 100000
#define N_ITEMS 50000
#define N_NODES 150000
#define DD 64
#define E_G 3200000
#define EU 1600000
#define EI 800000
#define E_HAN 4800000
#define NH 300000
#define NBG 293        // ceil(150000/512)
#define NBH 586        // ceil(300000/512)
#define ROWS 32
#define NBU 3125       // ceil(100000/32)
#define NBI 1563       // ceil(50000/32)

typedef float v2f __attribute__((ext_vector_type(2)));

__device__ __forceinline__ float invdeg(float d){
  return d > 0.f ? rsqrtf(fmaxf(d, 1e-12f)) : 0.f;
}
__device__ __forceinline__ float tanh_fast(float x){
  float cx = fminf(15.f, fmaxf(-15.f, x));
  float t = __expf(2.f*cx);
  return (t - 1.f)/(t + 1.f);
}
__device__ __forceinline__ unsigned short f2b(float x){
  unsigned int b = __float_as_uint(x);
  b += 0x7FFFu + ((b >> 16) & 1u);
  return (unsigned short)(b >> 16);
}
__device__ __forceinline__ float b2f(unsigned short u){
  return __uint_as_float(((unsigned int)u) << 16);
}
// unpack 2 bf16 (lo,hi) from one uint into a float2 vector (pk_fma friendly)
__device__ __forceinline__ v2f b2f2(unsigned int u){
  v2f r;
  r.x = __uint_as_float(u << 16);
  r.y = __uint_as_float(u & 0xFFFF0000u);
  return r;
}
__device__ __forceinline__ unsigned short f2h(float x){
  return __half_as_ushort(__float2half(x));
}
__device__ __forceinline__ float h2f(unsigned short u){
  return __half2float(__ushort_as_half(u));
}
__device__ __forceinline__ v2f h2v2(unsigned int u){
  __half2 h = *reinterpret_cast<__half2*>(&u);
  float2 t = __half22float2(h);
  v2f r; r.x = t.x; r.y = t.y;
  return r;
}

__global__ void k_init(const float* __restrict__ fu, const float* __restrict__ fi,
                       float* __restrict__ cur, unsigned short* __restrict__ curh,
                       float* __restrict__ total){
  int i = blockIdx.x*256 + threadIdx.x;
  if (i >= N_NODES*DD) return;
  float v = (i < N_USERS*DD) ? fu[i] : fi[i - N_USERS*DD];
  cur[i] = v; total[i] = v; curh[i] = f2h(v);
}

// ---------------- generic scan helpers ----------------
__global__ __launch_bounds__(256) void k_colscan(int* __restrict__ wh, int nb,
                                                 int* __restrict__ colsum){
  __shared__ int s[256];
  int b = blockIdx.x, tid = threadIdx.x;
  int v = wh[tid*nb + b];
  s[tid] = v; __syncthreads();
  for (int o = 1; o < 256; o <<= 1){
    int t = (tid >= o) ? s[tid - o] : 0;
    __syncthreads();
    s[tid] += t;
    __syncthreads();
  }
  wh[tid*nb + b] = s[tid] - v;
  if (tid == 255) colsum[b] = s[255];
}

__global__ __launch_bounds__(256) void k_bscan(const int* __restrict__ colsum, int nb,
                                               int total, int* __restrict__ bB){
  __shared__ int s[256];
  __shared__ int carry;
  int tid = threadIdx.x;
  if (tid == 0) carry = 0;
  __syncthreads();
  for (int base = 0; base < nb; base += 256){
    int i = base + tid;
    int v = (i < nb) ? colsum[i] : 0;
    s[tid] = v; __syncthreads();
    for (int o = 1; o < 256; o <<= 1){
      int t = (tid >= o) ? s[tid - o] : 0;
      __syncthreads();
      s[tid] += t;
      __syncthreads();
    }
    int c = carry;
    if (i < nb) bB[i] = c + s[tid] - v;
    __syncthreads();
    if (tid == 255) carry = c + s[255];
    __syncthreads();
  }
  if (tid == 0) bB[nb] = total;
}

// ---------------- G build ----------------
__global__ __launch_bounds__(256) void k_h1_g(const int* __restrict__ gi,
                                              int* __restrict__ wh){
  __shared__ int h[NBG];
  int tid = threadIdx.x;
  for (int b = tid; b < NBG; b += 256) h[b] = 0;
  __syncthreads();
  int e0 = blockIdx.x*(E_G/256);
  for (int i = tid; i < E_G/256; i += 256)
    atomicAdd(&h[gi[e0 + i] >> 9], 1);
  __syncthreads();
  for (int b = tid; b < NBG; b += 256) wh[blockIdx.x*NBG + b] = h[b];
}

__global__ __launch_bounds__(256) void k_h2_g(const int* __restrict__ gi,
        const float* __restrict__ gv, const int* __restrict__ wh,
        const int* __restrict__ bB, uint2* __restrict__ kv){
  __shared__ int lcur[NBG];
  int tid = threadIdx.x, wg = blockIdx.x;
  for (int b = tid; b < NBG; b += 256) lcur[b] = bB[b] + wh[wg*NBG + b];
  __syncthreads();
  int e0 = wg*(E_G/256);
  for (int i = tid; i < E_G/256; i += 256){
    int e = e0 + i;
    int d = gi[e];
    int p = atomicAdd(&lcur[d >> 9], 1);
    uint2 r;
    r.x = ((unsigned)(d & 511) << 18) | (unsigned)gi[E_G + e];
    r.y = __float_as_uint(gv[e]);
    kv[p] = r;
  }
}

__global__ __launch_bounds__(256) void k_p2_g(const int* __restrict__ bB,
        const uint2* __restrict__ kv, int* __restrict__ off,
        unsigned int* __restrict__ packed){
  __shared__ int cnt[512], sc[512], lcur[512];
  int b = blockIdx.x, tid = threadIdx.x;
  int d0 = b << 9;
  int dcnt = min(512, N_NODES - d0);
  int pb = bB[b], pe = bB[b+1];
  for (int i = tid; i < 512; i += 256) cnt[i] = 0;
  __syncthreads();
  for (int p = pb + tid; p < pe; p += 256)
    atomicAdd(&cnt[kv[p].x >> 18], 1);
  __syncthreads();
  sc[tid] = cnt[tid]; sc[tid + 256] = cnt[tid + 256];
  __syncthreads();
  for (int o = 1; o < 512; o <<= 1){
    int a0 = (tid >= o) ? sc[tid - o] : 0;
    int a1 = sc[tid + 256 - o];
    __syncthreads();
    sc[tid] += a0; sc[tid + 256] += a1;
    __syncthreads();
  }
  for (int i = tid; i < 512; i += 256) lcur[i] = pb + sc[i] - cnt[i];
  for (int i = tid; i < dcnt; i += 256) off[d0 + i] = pb + sc[i] - cnt[i];
  if (tid == 0) off[d0 + dcnt] = pe;
  __syncthreads();
  for (int p = pb + tid; p < pe; p += 256){
    uint2 r = kv[p];
    int dl = (int)(r.x >> 18);
    unsigned int s = r.x & 0x3FFFFu;
    float v = __uint_as_float(r.y);
    int q14 = (int)(v*16383.f + 0.5f);
    if (q14 > 16383) q14 = 16383;
    int q = atomicAdd(&lcur[dl], 1);
    packed[q] = (s << 14) | (unsigned int)q14;
  }
}

// ---------------- DCCF spmm gather (packed CSR, f16 table, 2 gathers in flight) ----
__global__ __launch_bounds__(256) void k_spmm_gp(const int* __restrict__ off,
        const unsigned int* __restrict__ packed,
        const unsigned short* __restrict__ curh, unsigned short* __restrict__ gnnh){
  int wv = threadIdx.x >> 6, lane = threadIdx.x & 63;
  int node = blockIdx.x*4 + wv;
  if (node >= N_NODES) return;
  int b = off[node], e = off[node+1];
  int c8 = (lane & 7)*8, sl = lane >> 3;
  const float inv14 = 1.f/16383.f;
  v2f a0 = {0.f,0.f}, a1 = {0.f,0.f}, a2 = {0.f,0.f}, a3 = {0.f,0.f};
  for (int k = b; k < e; k += 16){
    int i0 = k + sl, i1 = i0 + 8;
    unsigned int pk0 = (i0 < e) ? packed[i0] : 0u;   // pk==0 -> weight 0
    unsigned int pk1 = (i1 < e) ? packed[i1] : 0u;
    int s0 = (int)(pk0 >> 14), s1 = (int)(pk1 >> 14);
    float w0 = (float)(pk0 & 16383u) * inv14;
    float w1 = (float)(pk1 & 16383u) * inv14;
    const uint4 u0 = *(const uint4*)&curh[s0*DD + c8];
    const uint4 u1 = *(const uint4*)&curh[s1*DD + c8];
    a0 += w0 * h2v2(u0.x); a1 += w0 * h2v2(u0.y);
    a2 += w0 * h2v2(u0.z); a3 += w0 * h2v2(u0.w);
    a0 += w1 * h2v2(u1.x); a1 += w1 * h2v2(u1.y);
    a2 += w1 * h2v2(u1.z); a3 += w1 * h2v2(u1.w);
  }
  float a[8] = {a0.x,a0.y,a1.x,a1.y,a2.x,a2.y,a3.x,a3.y};
  #pragma unroll
  for (int j = 0; j < 8; ++j){
    a[j] += __shfl_xor(a[j], 8, 64);
    a[j] += __shfl_xor(a[j], 16, 64);
    a[j] += __shfl_xor(a[j], 32, 64);
  }
  if (lane < 8){
    uint4 o;
    o.x = (unsigned)f2h(a[0]) | ((unsigned)f2h(a[1]) << 16);
    o.y = (unsigned)f2h(a[2]) | ((unsigned)f2h(a[3]) << 16);
    o.z = (unsigned)f2h(a[4]) | ((unsigned)f2h(a[5]) << 16);
    o.w = (unsigned)f2h(a[6]) | ((unsigned)f2h(a[7]) << 16);
    *(uint4*)&gnnh[node*DD + c8] = o;
  }
}

// ---------------- intent (tiled GEMM, user+item merged, conflict-free LDS) ------
// col ownership: thread (tx,ty) handles cols {4tx..4tx+3, 64+4tx..64+4tx+3}
// PV output dims: d = tx + 16m  (lane stride 132 floats = 4 banks -> 2-way)
__global__ __launch_bounds__(256) void k_intent2(const float* __restrict__ u_int,
        const float* __restrict__ i_int,
        const unsigned short* __restrict__ gnnh, float* __restrict__ cur,
        unsigned short* __restrict__ curh, float* __restrict__ total){
  __shared__ float sB[64*132];
  __shared__ float sU[ROWS*132];
  int tid = threadIdx.x, tx = tid & 15, ty = tid >> 4;
  int bid = blockIdx.x;
  const float* intent; int base, nrows, lb;
  if (bid < NBU){ intent = u_int; base = 0; nrows = N_USERS; lb = bid; }
  else          { intent = i_int; base = N_USERS; nrows = N_ITEMS; lb = bid - NBU; }

  for (int i = tid; i < 2048; i += 256){
    int r = i >> 5, c = (i & 31) << 2;
    *(float4*)&sB[r*132 + c] = *(const float4*)&intent[r*128 + c];
  }
  {
    int r = tid & 31, q0 = tid >> 5;
    int rr = lb*ROWS + r;
    int rowg = base + (rr < nrows ? rr : nrows - 1);
    for (int q = q0; q < 16; q += 8){
      float4 v = *(const float4*)&cur[rowg*DD + 4*q];
      sU[(4*q+0)*36 + r] = v.x;
      sU[(4*q+1)*36 + r] = v.y;
      sU[(4*q+2)*36 + r] = v.z;
      sU[(4*q+3)*36 + r] = v.w;
    }
  }
  __syncthreads();

  float w[2][8];
  #pragma unroll
  for (int i = 0; i < 2; ++i)
    #pragma unroll
    for (int k = 0; k < 8; ++k) w[i][k] = 0.f;
  for (int d = 0; d < 64; ++d){
    float2 a = *(const float2*)&sU[d*36 + 2*ty];
    float4 b0 = *(const float4*)&sB[d*132 + 4*tx];        // banks stride 4 -> 2-way
    float4 b1 = *(const float4*)&sB[d*132 + 64 + 4*tx];
    float bb[8] = {b0.x,b0.y,b0.z,b0.w,b1.x,b1.y,b1.z,b1.w};
    #pragma unroll
    for (int k = 0; k < 8; ++k){ w[0][k] += a.x*bb[k]; w[1][k] += a.y*bb[k]; }
  }

  float p[2][8];
  #pragma unroll
  for (int i = 0; i < 2; ++i){
    float mx = w[i][0];
    #pragma unroll
    for (int k = 1; k < 8; ++k) mx = fmaxf(mx, w[i][k]);
    mx = fmaxf(mx, __shfl_xor(mx, 1, 64));
    mx = fmaxf(mx, __shfl_xor(mx, 2, 64));
    mx = fmaxf(mx, __shfl_xor(mx, 4, 64));
    mx = fmaxf(mx, __shfl_xor(mx, 8, 64));
    float s = 0.f;
    #pragma unroll
    for (int k = 0; k < 8; ++k){ p[i][k] = __expf(w[i][k] - mx); s += p[i][k]; }
    s += __shfl_xor(s, 1, 64);
    s += __shfl_xor(s, 2, 64);
    s += __shfl_xor(s, 4, 64);
    s += __shfl_xor(s, 8, 64);
    float inv = 1.f / s;
    #pragma unroll
    for (int k = 0; k < 8; ++k) p[i][k] *= inv;
  }
  __syncthreads();
  #pragma unroll
  for (int i = 0; i < 2; ++i){
    *(float4*)&sU[(2*ty+i)*132 + 4*tx]      = make_float4(p[i][0],p[i][1],p[i][2],p[i][3]);
    *(float4*)&sU[(2*ty+i)*132 + 64 + 4*tx] = make_float4(p[i][4],p[i][5],p[i][6],p[i][7]);
  }
  __syncthreads();

  float o[2][4];
  #pragma unroll
  for (int i = 0; i < 2; ++i)
    #pragma unroll
    for (int m = 0; m < 4; ++m) o[i][m] = 0.f;
  for (int q = 0; q < 32; ++q){
    float4 p0 = *(const float4*)&sU[(2*ty+0)*132 + 4*q];
    float4 p1 = *(const float4*)&sU[(2*ty+1)*132 + 4*q];
    #pragma unroll
    for (int m = 0; m < 4; ++m){
      float4 bl = *(const float4*)&sB[(tx + 16*m)*132 + 4*q];  // 2-way
      o[0][m] += p0.x*bl.x + p0.y*bl.y + p0.z*bl.z + p0.w*bl.w;
      o[1][m] += p1.x*bl.x + p1.y*bl.y + p1.z*bl.z + p1.w*bl.w;
    }
  }

  #pragma unroll
  for (int i = 0; i < 2; ++i){
    int rr = lb*ROWS + 2*ty + i;
    if (rr < nrows){
      int rowg = base + rr;
      #pragma unroll
      for (int m = 0; m < 4; ++m){
        int col = tx + 16*m;
        float g = h2f(gnnh[rowg*DD + col]);
        float c = cur[rowg*DD + col];
        float t = total[rowg*DD + col];
        float cn = g + o[i][m] + c;
        cur[rowg*DD + col] = cn;
        curh[rowg*DD + col] = f2h(cn);
        total[rowg*DD + col] = t + cn;
      }
    }
  }
}

// ---------------- HAN build ----------------
__device__ __forceinline__ void han_decode(int t, const int* mp_u, const int* mp_i,
                                           int* gs, int* gd){
  if (t < 2*EU){
    int s = (t < EU) ? 0 : 1;
    int e = t - s*EU;
    const int* sp = mp_u + (long)s*2*EU;
    int nb = s*N_USERS;
    *gs = nb + sp[e]; *gd = nb + sp[EU + e];
  } else {
    int t2 = t - 2*EU;
    int s = (t2 < EI) ? 0 : 1;
    int e = t2 - s*EI;
    const int* sp = mp_i + (long)s*2*EI;
    int nb = 2*N_USERS + s*N_ITEMS;
    *gs = nb + sp[e]; *gd = nb + sp[EI + e];
  }
}

// dst-bucket + src-bucket histograms (per-wg, LDS)
__global__ __launch_bounds__(256) void k_h1_h(const int* __restrict__ mp_u,
        const int* __restrict__ mp_i, int* __restrict__ whD, int* __restrict__ whS){
  __shared__ int hd[NBH], hs[NBH];
  int tid = threadIdx.x;
  for (int b = tid; b < NBH; b += 256){ hd[b] = 0; hs[b] = 0; }
  __syncthreads();
  int t0 = blockIdx.x*(E_HAN/256);
  for (int i = tid; i < E_HAN/256; i += 256){
    int gs, gd;
    han_decode(t0 + i, mp_u, mp_i, &gs, &gd);
    atomicAdd(&hd[gd >> 9], 1);
    atomicAdd(&hs[gs >> 9], 1);
  }
  __syncthreads();
  for (int b = tid; b < NBH; b += 256){
    whD[blockIdx.x*NBH + b] = hd[b];
    whS[blockIdx.x*NBH + b] = hs[b];
  }
}

__global__ __launch_bounds__(256) void k_h2_h(const int* __restrict__ mp_u,
        const int* __restrict__ mp_i, const int* __restrict__ whD,
        const int* __restrict__ whS, const int* __restrict__ bBD,
        const int* __restrict__ bBS, unsigned int* __restrict__ keyD,
        unsigned short* __restrict__ keyS){
  __shared__ int lcD[NBH], lcS[NBH];
  int tid = threadIdx.x, wg = blockIdx.x;
  for (int b = tid; b < NBH; b += 256){
    lcD[b] = bBD[b] + whD[wg*NBH + b];
    lcS[b] = bBS[b] + whS[wg*NBH + b];
  }
  __syncthreads();
  int t0 = wg*(E_HAN/256);
  for (int i = tid; i < E_HAN/256; i += 256){
    int gs, gd;
    han_decode(t0 + i, mp_u, mp_i, &gs, &gd);
    int pD = atomicAdd(&lcD[gd >> 9], 1);
    keyD[pD] = ((unsigned)(gd & 511) << 19) | (unsigned)gs;
    int pS = atomicAdd(&lcS[gs >> 9], 1);
    keyS[pS] = (unsigned short)(gs & 511);   // within-bucket index only
  }
}

// per-bucket LDS count of bucket-sorted ushort keys -> src out-degrees
__global__ __launch_bounds__(256) void k_cnt_hs(const int* __restrict__ bB,
        const unsigned short* __restrict__ keyS, int* __restrict__ dego){
  __shared__ int cnt[512];
  int b = blockIdx.x, tid = threadIdx.x;
  int d0 = b << 9;
  int dcnt = min(512, NH - d0);
  int pb = bB[b], pe = bB[b+1];
  for (int i = tid; i < 512; i += 256) cnt[i] = 0;
  __syncthreads();
  for (int p = pb + tid; p < pe; p += 256)
    atomicAdd(&cnt[keyS[p]], 1);
  __syncthreads();
  for (int i = tid; i < dcnt; i += 256) dego[d0 + i] = cnt[i];
}

// partition keyD by dst; pack ssrc = (feat_row(src) << 14) | q14(invdeg(degout[src]))
__global__ __launch_bounds__(256) void k_p2_h(const int* __restrict__ bB,
        const unsigned int* __restrict__ key, const int* __restrict__ dego,
        int* __restrict__ off, unsigned int* __restrict__ ssrc){
  __shared__ int cnt[512], sc[512], lcur[512];
  int b = blockIdx.x, tid = threadIdx.x;
  int d0 = b << 9;
  int dcnt = min(512, NH - d0);
  int pb = bB[b], pe = bB[b+1];
  for (int i = tid; i < 512; i += 256) cnt[i] = 0;
  __syncthreads();
  for (int p = pb + tid; p < pe; p += 256)
    atomicAdd(&cnt[key[p] >> 19], 1);
  __syncthreads();
  sc[tid] = cnt[tid]; sc[tid + 256] = cnt[tid + 256];
  __syncthreads();
  for (int o = 1; o < 512; o <<= 1){
    int a0 = (tid >= o) ? sc[tid - o] : 0;
    int a1 = sc[tid + 256 - o];
    __syncthreads();
    sc[tid] += a0; sc[tid + 256] += a1;
    __syncthreads();
  }
  for (int i = tid; i < 512; i += 256) lcur[i] = pb + sc[i] - cnt[i];
  for (int i = tid; i < dcnt; i += 256) off[d0 + i] = pb + sc[i] - cnt[i];
  if (tid == 0) off[d0 + dcnt] = pe;
  __syncthreads();
  for (int p = pb + tid; p < pe; p += 256){
    unsigned int k = key[p];
    int dl = (int)(k >> 19);
    int gs = (int)(k & 0x7FFFFu);
    // map HAN node id -> shared feature row [0,150000)
    int fsrc = gs - (gs >= N_USERS ? N_USERS : 0) - (gs >= 250000 ? 50000 : 0);
    float w = invdeg((float)dego[gs]);
    int q14 = (int)(w*16383.f + 0.5f);
    if (q14 > 16383) q14 = 16383;
    int q = atomicAdd(&lcur[dl], 1);
    ssrc[q] = ((unsigned)fsrc << 14) | (unsigned)q14;
  }
}

// fb[row] = bf16(feat[row]) for the shared 150K-row feature table
__global__ void k_fb(const float* __restrict__ fu, const float* __restrict__ fi,
                     unsigned short* __restrict__ fb){
  int i = blockIdx.x*256 + threadIdx.x;
  if (i >= N_NODES*DD) return;
  float f = (i < N_USERS*DD) ? fu[i] : fi[i - N_USERS*DD];
  fb[i] = f2b(f);
}

// z[g] (bf16) = invdeg(deg_in[g]) * sum q14(invdeg_out[src]) * fb[src]
// 8 lanes/edge x 16B loads, 16 edges per iteration, 2 gathers in flight/lane
__global__ __launch_bounds__(256) void k_han_gb(const int* __restrict__ off,
        const unsigned int* __restrict__ ssrc, const unsigned short* __restrict__ fb,
        unsigned short* __restrict__ zb){
  int wv = threadIdx.x >> 6, lane = threadIdx.x & 63;
  int g = blockIdx.x*4 + wv;
  if (g >= NH) return;
  int b = off[g], e = off[g+1];
  int c8 = (lane & 7)*8, sl = lane >> 3;
  const float inv14 = 1.f/16383.f;
  v2f a0 = {0.f,0.f}, a1 = {0.f,0.f}, a2 = {0.f,0.f}, a3 = {0.f,0.f};
  for (int k = b; k < e; k += 16){
    int i0 = k + sl, i1 = i0 + 8;
    unsigned int pk0 = (i0 < e) ? ssrc[i0] : 0u;   // pk==0 -> weight 0
    unsigned int pk1 = (i1 < e) ? ssrc[i1] : 0u;
    int s0 = (int)(pk0 >> 14), s1 = (int)(pk1 >> 14);
    float w0 = (float)(pk0 & 16383u) * inv14;
    float w1 = (float)(pk1 & 16383u) * inv14;
    const uint4 u0 = *(const uint4*)&fb[s0*DD + c8];
    const uint4 u1 = *(const uint4*)&fb[s1*DD + c8];
    a0 += w0 * b2f2(u0.x); a1 += w0 * b2f2(u0.y);
    a2 += w0 * b2f2(u0.z); a3 += w0 * b2f2(u0.w);
    a0 += w1 * b2f2(u1.x); a1 += w1 * b2f2(u1.y);
    a2 += w1 * b2f2(u1.z); a3 += w1 * b2f2(u1.w);
  }
  float a[8] = {a0.x,a0.y,a1.x,a1.y,a2.x,a2.y,a3.x,a3.y};
  #pragma unroll
  for (int j = 0; j < 8; ++j){
    a[j] += __shfl_xor(a[j], 8, 64);
    a[j] += __shfl_xor(a[j], 16, 64);
    a[j] += __shfl_xor(a[j], 32, 64);
  }
  if (lane < 8){
    float win = invdeg((float)(e - b));
    uint4 o;
    o.x = (unsigned)f2b(win*a[0]) | ((unsigned)f2b(win*a[1]) << 16);
    o.y = (unsigned)f2b(win*a[2]) | ((unsigned)f2b(win*a[3]) << 16);
    o.z = (unsigned)f2b(win*a[4]) | ((unsigned)f2b(win*a[5]) << 16);
    o.w = (unsigned)f2b(win*a[6]) | ((unsigned)f2b(win*a[7]) << 16);
    *(uint4*)&zb[g*DD + c8] = o;
  }
}

// semantic attention reduction (bf16 z input), user+item merged, conflict-free LDS
__global__ __launch_bounds__(256) void k_sem2(const float* __restrict__ uW1,
        const float* __restrict__ ub1, const float* __restrict__ uw2,
        const float* __restrict__ iW1, const float* __restrict__ ib1,
        const float* __restrict__ iw2, const unsigned short* __restrict__ zb,
        float* __restrict__ wsum){
  __shared__ float sW[64*132];
  __shared__ float sA[64*36];
  __shared__ float sBias[128], sV[128];
  __shared__ float red[2];
  int tid = threadIdx.x, tx = tid & 15, ty = tid >> 4;
  int bid = blockIdx.x;
  const float *W1, *b1, *w2; const unsigned short* z; int nn, lb, wo;
  if (bid < NBU){ W1 = uW1; b1 = ub1; w2 = uw2; z = zb; nn = N_USERS; lb = bid; wo = 0; }
  else { W1 = iW1; b1 = ib1; w2 = iw2; z = zb + (long)2*N_USERS*DD;
         nn = N_ITEMS; lb = bid - NBU; wo = 2; }

  for (int i = tid; i < 2048; i += 256){
    int r = i >> 5, c = (i & 31) << 2;
    *(float4*)&sW[r*132 + c] = *(const float4*)&W1[r*128 + c];
  }
  if (tid < 128){ sBias[tid] = b1[tid]; sV[tid] = w2[tid]; }
  if (tid < 2) red[tid] = 0.f;

  for (int m = 0; m < 2; ++m){
    __syncthreads();
    {
      int r = tid & 31, q0 = tid >> 5;
      int rr = lb*ROWS + r;
      int rowg = (rr < nn ? rr : nn - 1) + m*nn;
      for (int q = q0; q < 16; q += 8){
        ushort4 v = *(const ushort4*)&z[(long)rowg*DD + 4*q];
        sA[(4*q+0)*36 + r] = b2f(v.x);
        sA[(4*q+1)*36 + r] = b2f(v.y);
        sA[(4*q+2)*36 + r] = b2f(v.z);
        sA[(4*q+3)*36 + r] = b2f(v.w);
      }
    }
    __syncthreads();

    float w[2][8];
    #pragma unroll
    for (int i = 0; i < 2; ++i)
      #pragma unroll
      for (int k = 0; k < 8; ++k)
        w[i][k] = sBias[(k < 4 ? 4*tx + k : 64 + 4*tx + k - 4)];
    for (int d = 0; d < 64; ++d){
      float2 a = *(const float2*)&sA[d*36 + 2*ty];
      float4 b0 = *(const float4*)&sW[d*132 + 4*tx];        // 2-way
      float4 b4 = *(const float4*)&sW[d*132 + 64 + 4*tx];
      float bb[8] = {b0.x,b0.y,b0.z,b0.w,b4.x,b4.y,b4.z,b4.w};
      #pragma unroll
      for (int k = 0; k < 8; ++k){ w[0][k] += a.x*bb[k]; w[1][k] += a.y*bb[k]; }
    }
    float part = 0.f;
    #pragma unroll
    for (int i = 0; i < 2; ++i){
      int rr = lb*ROWS + 2*ty + i;
      if (rr < nn){
        #pragma unroll
        for (int k = 0; k < 8; ++k)
          part += tanh_fast(w[i][k]) * sV[(k < 4 ? 4*tx + k : 64 + 4*tx + k - 4)];
      }
    }
    part += __shfl_xor(part, 1, 64);
    part += __shfl_xor(part, 2, 64);
    part += __shfl_xor(part, 4, 64);
    part += __shfl_xor(part, 8, 64);
    part += __shfl_xor(part, 16, 64);
    part += __shfl_xor(part, 32, 64);
    if ((tid & 63) == 0) atomicAdd(&red[m], part);
  }
  __syncthreads();
  if (tid < 2) atomicAdd(&wsum[wo + tid], red[tid]);
}

__global__ void k_beta(const float* __restrict__ wsum, float* __restrict__ beta){
  if (threadIdx.x == 0 && blockIdx.x == 0){
    float u0 = wsum[0] / (float)N_USERS, u1 = wsum[1] / (float)N_USERS;
    float m = fmaxf(u0, u1);
    float e0 = __expf(u0 - m), e1 = __expf(u1 - m);
    beta[0] = e0/(e0+e1); beta[1] = e1/(e0+e1);
    float i0 = wsum[2] / (float)N_ITEMS, i1 = wsum[3] / (float)N_ITEMS;
    m = fmaxf(i0, i1);
    e0 = __expf(i0 - m); e1 = __expf(i1 - m);
    beta[2] = e0/(e0+e1); beta[3] = e1/(e0+e1);
  }
}

__global__ void k_final(const float* __restrict__ total, const unsigned short* __restrict__ zb,
                        const float* __restrict__ beta, float* __restrict__ out){
  int i = blockIdx.x*256 + threadIdx.x;
  if (i >= N_NODES*DD) return;
  float h;
  if (i < N_USERS*DD)
    h = beta[0]*b2f(zb[i]) + beta[1]*b2f(zb[N_USERS*DD + i]);
  else {
    int j = i - N_USERS*DD;
    h = beta[2]*b2f(zb[2*N_USERS*DD + j]) + beta[3]*b2f(zb[(2*N_USERS + N_ITEMS)*DD + j]);
  }
  out[i] = 0.5f*total[i] + 0.5f*h;
}

extern "C" void kernel_launch(void* const* d_in, const int* in_sizes, int n_in,
                              void* d_out, int out_size, void* d_ws, size_t ws_size,
                              hipStream_t stream) {
  const int*   G_idx = (const int*)d_in[0];
  const float* G_val = (const float*)d_in[1];
  const float* fu    = (const float*)d_in[2];
  const float* fi    = (const float*)d_in[3];
  const float* u_int = (const float*)d_in[4];
  const float* i_int = (const float*)d_in[5];
  const int*   mp_u  = (const int*)d_in[6];
  const int*   mp_i  = (const int*)d_in[7];
  const float* uW1   = (const float*)d_in[8];
  const float* ub1   = (const float*)d_in[9];
  const float* uw2   = (const float*)d_in[10];
  const float* iW1   = (const float*)d_in[11];
  const float* ib1   = (const float*)d_in[12];
  const float* iw2   = (const float*)d_in[13];
  float* out = (float*)d_out;

  float* ws = (float*)d_ws;
  // Phase A (G build + layers):
  float*        total  = ws;                                // [0, 9.6M)
  float*        cur    = ws + 9600000;                      // [9.6M, 19.2M)
  unsigned short* gnnh = (unsigned short*)(ws + 19200000);  // [19.2M, 24M) f16 9.6M elems
  unsigned short* curh = (unsigned short*)(ws + 24000000);  // [24M, 28.8M) f16 9.6M elems
  uint2*        kvG    = (uint2*)ws;                        // [0, 6.4M) dead before k_init
  unsigned int* packG  = (unsigned int*)(ws + 28800000);    // [28.8M, 32.0M)
  int*          offG   = (int*)(ws + 33700000);             // 150001
  int*          whG    = (int*)(ws + 34930000);             // 256*293 = 75008
  int*          colG   = (int*)(ws + 35018000);             // 293
  int*          bBG    = (int*)(ws + 35019000);             // 294
  // Phase B (HAN):
  unsigned int* keyH   = (unsigned int*)(ws + 9600000);     // [9.6M,14.4M) dead before zb
  unsigned short* zb   = (unsigned short*)(ws + 9600000);   // [9.6M,19.2M)
  unsigned short* keyS = (unsigned short*)(ws + 19200000);  // [19.2M,21.6M) 4.8M ushort, dead before fb
  unsigned short* fb   = (unsigned short*)(ws + 19200000);  // [19.2M,24M) 150K*64 bf16
  unsigned int* ssrcH  = (unsigned int*)(ws + 28800000);    // [28.8M,33.6M)
  int*          degoH  = (int*)(ws + 34000000);             // 300k
  int*          offH   = (int*)(ws + 34300000);             // 300001
  int*          whH    = (int*)(ws + 34610000);             // 256*586 = 150016
  int*          whS    = (int*)(ws + 34770000);             // 150016
  int*          colH   = (int*)(ws + 35010000);             // 586
  int*          bBH    = (int*)(ws + 35012000);             // 587
  int*          colS   = (int*)(ws + 35014000);             // 586
  int*          bBS    = (int*)(ws + 35016000);             // 587
  float*        wsum   = ws + 35030000;                     // 4
  float*        beta   = ws + 35030004;                     // 4

  hipMemsetAsync(wsum, 0, 4*sizeof(float), stream);

  // ---- G CSR build (atomic-free partition; before k_init: kvG aliases total/cur) ----
  k_h1_g<<<256, 256, 0, stream>>>(G_idx, whG);
  k_colscan<<<NBG, 256, 0, stream>>>(whG, NBG, colG);
  k_bscan<<<1, 256, 0, stream>>>(colG, NBG, E_G, bBG);
  k_h2_g<<<256, 256, 0, stream>>>(G_idx, G_val, whG, bBG, kvG);
  k_p2_g<<<NBG, 256, 0, stream>>>(bBG, kvG, offG, packG);

  k_init<<<(N_NODES*DD + 255)/256, 256, 0, stream>>>(fu, fi, cur, curh, total);

  // ---- DCCF layers (spmm gathers f16 curh, writes f16 gnnh; intent merged u+i) ----
  for (int layer = 0; layer < 2; ++layer){
    k_spmm_gp<<<(N_NODES + 3)/4, 256, 0, stream>>>(offG, packG, curh, gnnh);
    k_intent2<<<NBU + NBI, 256, 0, stream>>>(u_int, i_int, gnnh, cur, curh, total);
  }

  // ---- HAN build (atomic-free partition; dego via bucket-sorted LDS count) ----
  k_h1_h<<<256, 256, 0, stream>>>(mp_u, mp_i, whH, whS);
  k_colscan<<<NBH, 256, 0, stream>>>(whH, NBH, colH);
  k_bscan<<<1, 256, 0, stream>>>(colH, NBH, E_HAN, bBH);
  k_colscan<<<NBH, 256, 0, stream>>>(whS, NBH, colS);
  k_bscan<<<1, 256, 0, stream>>>(colS, NBH, E_HAN, bBS);
  k_h2_h<<<256, 256, 0, stream>>>(mp_u, mp_i, whH, whS, bBH, bBS, keyH, keyS);
  k_cnt_hs<<<NBH, 256, 0, stream>>>(bBS, keyS, degoH);   // consumes keyS (before fb write)
  k_fb<<<(N_NODES*DD + 255)/256, 256, 0, stream>>>(fu, fi, fb);
  k_p2_h<<<NBH, 256, 0, stream>>>(bBH, keyH, degoH, offH, ssrcH);
  k_han_gb<<<(NH + 3)/4, 256, 0, stream>>>(offH, ssrcH, fb, zb);

  // ---- semantic attention (merged u+i) + combine ----
  k_sem2<<<NBU + NBI, 256, 0, stream>>>(uW1, ub1, uw2, iW1, ib1, iw2, zb, wsum);
  k_beta<<<1, 64, 0, stream>>>(wsum, beta);
  k_final<<<(N_NODES*DD + 255)/256, 256, 0, stream>>>(total, zb, beta, out);
}